// Round 7
// baseline (936.359 us; speedup 1.0000x reference)
//
#include <hip/hip_runtime.h>
#include <math.h>

// Problem constants: B=4, L=2048, D=1024, H=4, dk=dv=256, CHUNK=32, NCHUNK=64
// bf16 MFMA for all large GEMMs AND the delta-rule scan (shared-staged, dbuf,
// 4-wave blocks, counted vmcnt + raw s_barrier).

typedef __attribute__((ext_vector_type(8))) __bf16 bf16x8;
typedef __attribute__((ext_vector_type(4))) float f32x4;

__device__ inline ushort f2bf(float f) {
    union { float f; unsigned u; } x; x.f = f;
    unsigned u = x.u;
    u += 0x7fffu + ((u >> 16) & 1u);
    return (ushort)(u >> 16);
}
__device__ inline float bf2f(ushort h) {
    union { unsigned u; float f; } x; x.u = ((unsigned)h) << 16;
    return x.f;
}
__device__ inline float ldf(float v) { return v; }
__device__ inline float ldf(ushort v) { return bf2f(v); }

// ---------------------------------------------------------------------------
// bf16 MFMA GEMM: C[M,N] = A[M,K] @ BT[N,K]^T. 128x128 tile, BK=32, 4 waves.
// EPI 0: f32 out. 1: bf16 out. 3: bias+rank12+gelu, bf16 out.
// ---------------------------------------------------------------------------
template<int EPI>
__global__ __launch_bounds__(256) void gemm_mfma(
    const ushort* __restrict__ A, const ushort* __restrict__ BT,
    const float* __restrict__ bias, const float* __restrict__ extA,
    const float* __restrict__ extB, void* __restrict__ Cout,
    int M, int N, int K)
{
    __shared__ ushort As[128 * 32];
    __shared__ ushort Bs[128 * 32];
    __shared__ float bns[(EPI >= 2) ? 128 * 13 : 1];
    __shared__ float exb[(EPI >= 2) ? 12 * 128 : 1];
    const int tid = threadIdx.x;
    const int row0 = blockIdx.y * 128, col0 = blockIdx.x * 128;
    const int lane = tid & 63, wave = tid >> 6;
    const int wr = (wave >> 1) * 64, wc = (wave & 1) * 64;

    if (EPI >= 2) {
        for (int e = tid; e < 128 * 12; e += 256)
            bns[(e / 12) * 13 + (e % 12)] = extA[(long)(row0 + e / 12) * 12 + e % 12];
        for (int e = tid; e < 12 * 128; e += 256)
            exb[e] = extB[(long)(e >> 7) * N + col0 + (e & 127)];
    }

    f32x4 acc[4][4];
    #pragma unroll
    for (int m = 0; m < 4; ++m)
        #pragma unroll
        for (int n = 0; n < 4; ++n) {
            acc[m][n][0] = 0.f; acc[m][n][1] = 0.f;
            acc[m][n][2] = 0.f; acc[m][n][3] = 0.f;
        }

    const int rA = lane & 15;
    const int ko = (lane >> 4) * 8;
    const int srow = tid >> 2;
    const int skk = (tid & 3) * 8;

    for (int k0 = 0; k0 < K; k0 += 32) {
        #pragma unroll
        for (int i = 0; i < 2; ++i) {
            const long ga = (long)(row0 + i * 64 + srow) * K + k0 + skk;
            __builtin_amdgcn_global_load_lds(
                (const __attribute__((address_space(1))) void*)(A + ga),
                (__attribute__((address_space(3))) void*)(As + i * 2048 + wave * 512),
                16, 0, 0);
            const long gb = (long)(col0 + i * 64 + srow) * K + k0 + skk;
            __builtin_amdgcn_global_load_lds(
                (const __attribute__((address_space(1))) void*)(BT + gb),
                (__attribute__((address_space(3))) void*)(Bs + i * 2048 + wave * 512),
                16, 0, 0);
        }
        __syncthreads();
        bf16x8 af[4], bfr[4];
        #pragma unroll
        for (int m = 0; m < 4; ++m)
            af[m] = *(const bf16x8*)(As + (wr + m * 16 + rA) * 32 + ko);
        #pragma unroll
        for (int n = 0; n < 4; ++n)
            bfr[n] = *(const bf16x8*)(Bs + (wc + n * 16 + rA) * 32 + ko);
        #pragma unroll
        for (int m = 0; m < 4; ++m)
            #pragma unroll
            for (int n = 0; n < 4; ++n)
                acc[m][n] = __builtin_amdgcn_mfma_f32_16x16x32_bf16(af[m], bfr[n], acc[m][n], 0, 0, 0);
        __syncthreads();
    }

    const int crow = (lane >> 4) * 4;
    const int ccol = lane & 15;
    #pragma unroll
    for (int m = 0; m < 4; ++m) {
        #pragma unroll
        for (int n = 0; n < 4; ++n) {
            #pragma unroll
            for (int r = 0; r < 4; ++r) {
                const int rl = wr + m * 16 + crow + r;
                const int cl = wc + n * 16 + ccol;
                float vv = acc[m][n][r];
                if (EPI >= 2) {
                    vv += bias[col0 + cl];
                    #pragma unroll
                    for (int j = 0; j < 12; ++j) vv += bns[rl * 13 + j] * exb[j * 128 + cl];
                    vv = 0.5f * vv * (1.f + erff(vv * 0.70710678118654752f));
                }
                const long off = (long)(row0 + rl) * N + col0 + cl;
                if (EPI == 0) ((float*)Cout)[off] = vv;
                else ((ushort*)Cout)[off] = f2bf(vv);
            }
        }
    }
}

// ---------------------------------------------------------------------------
// Transpose + cast to bf16: W[K][N] f32 -> WT[N][K] bf16.
// ---------------------------------------------------------------------------
__global__ __launch_bounds__(256) void transpose_cast(const float* __restrict__ W,
    ushort* __restrict__ WT, int K, int N)
{
    __shared__ float t[32][33];
    const int k0 = blockIdx.y * 32, n0 = blockIdx.x * 32;
    const int c = threadIdx.x & 31, r8 = threadIdx.x >> 5;
    #pragma unroll
    for (int rr = 0; rr < 4; ++rr) {
        const int r = r8 + rr * 8;
        t[r][c] = W[(long)(k0 + r) * N + n0 + c];
    }
    __syncthreads();
    #pragma unroll
    for (int rr = 0; rr < 4; ++rr) {
        const int r = r8 + rr * 8;
        WT[(long)(n0 + r) * K + k0 + c] = f2bf(t[c][r]);
    }
}

__global__ __launch_bounds__(256) void cast_bf16(const float* __restrict__ x,
    ushort* __restrict__ y)
{
    const long i = ((long)blockIdx.x * 256 + threadIdx.x) * 4;
    const float4 v = *(const float4*)(x + i);
    ushort4 o;
    o.x = f2bf(v.x); o.y = f2bf(v.y); o.z = f2bf(v.z); o.w = f2bf(v.w);
    *(ushort4*)(y + i) = o;
}

// ---------------------------------------------------------------------------
// Small-N GEMM. MODE 0: sigmoid. MODE 1: +bias, per-head softmax over triples.
// ---------------------------------------------------------------------------
template<int NOUT, int MODE, typename TA>
__global__ __launch_bounds__(256) void gemm_smallN(const TA* __restrict__ A,
    const float* __restrict__ Bm, const float* __restrict__ bias,
    float* __restrict__ Cm, int K)
{
    __shared__ float part[4][NOUT];
    __shared__ float sm[NOUT];
    const int m = blockIdx.x, tid = threadIdx.x;
    const TA* ar = A + (long)m * K;
    float acc[NOUT];
    #pragma unroll
    for (int j = 0; j < NOUT; ++j) acc[j] = 0.f;
    for (int k = tid; k < K; k += 256) {
        const float a = ldf(ar[k]);
        #pragma unroll
        for (int j = 0; j < NOUT; ++j) acc[j] += a * Bm[(long)k * NOUT + j];
    }
    #pragma unroll
    for (int j = 0; j < NOUT; ++j)
        for (int off = 32; off > 0; off >>= 1) acc[j] += __shfl_down(acc[j], off);
    const int wid = tid >> 6, lane = tid & 63;
    if (lane == 0) {
        #pragma unroll
        for (int j = 0; j < NOUT; ++j) part[wid][j] = acc[j];
    }
    __syncthreads();
    if (tid < NOUT) {
        float s = part[0][tid] + part[1][tid] + part[2][tid] + part[3][tid];
        if (MODE == 0) {
            Cm[(long)m * NOUT + tid] = 1.f / (1.f + expf(-s));
        } else {
            sm[tid] = s + bias[tid];
        }
    }
    if (MODE == 1) {
        __syncthreads();
        if (tid < NOUT) {
            const int hh = tid / 3, r = tid - hh * 3;
            const float a0 = sm[hh * 3], a1 = sm[hh * 3 + 1], a2 = sm[hh * 3 + 2];
            const float mx = fmaxf(a0, fmaxf(a1, a2));
            const float e0 = expf(a0 - mx), e1 = expf(a1 - mx), e2 = expf(a2 - mx);
            const float mine = (r == 0) ? e0 : ((r == 1) ? e1 : e2);
            Cm[(long)m * NOUT + tid] = mine / (e0 + e1 + e2);
        }
    }
}

// ---------------------------------------------------------------------------
// Depthwise causal conv (k=4) + SiLU, fp32 -> fp32.
// ---------------------------------------------------------------------------
__global__ __launch_bounds__(256) void conv4_silu(const float* __restrict__ x,
    const float* __restrict__ wc, float* __restrict__ y)
{
    const long idx = (long)blockIdx.x * 256 + threadIdx.x;
    const int c = (int)(idx & 1023);
    const long bl = idx >> 10;
    const int l = (int)(bl & 2047);
    const long b = bl >> 11;
    const float* xp = x + b * 2048 * 1024 + c;
    const float* wp = wc + c * 4;
    float s = 0.f;
    #pragma unroll
    for (int t = 0; t < 4; ++t) {
        const int ll = l - 3 + t;
        if (ll >= 0) s += xp[(long)ll * 1024] * wp[t];
    }
    y[idx] = s / (1.f + expf(-s));
}

// ---------------------------------------------------------------------------
// l2 normalize rows of 256 (fp32 in), write bf16.
// ---------------------------------------------------------------------------
__global__ __launch_bounds__(256) void l2norm_bf16(const float* __restrict__ x,
    ushort* __restrict__ y)
{
    const long wid = ((long)blockIdx.x * 256 + threadIdx.x) >> 6;
    const int lane = threadIdx.x & 63;
    const float4 xv = *(const float4*)(x + wid * 256 + lane * 4);
    float ss = xv.x * xv.x + xv.y * xv.y + xv.z * xv.z + xv.w * xv.w;
    for (int off = 32; off > 0; off >>= 1) ss += __shfl_down(ss, off);
    ss = __shfl(ss, 0);
    const float inv = rsqrtf(ss + 1e-6f);
    ushort4 o;
    o.x = f2bf(xv.x * inv); o.y = f2bf(xv.y * inv);
    o.z = f2bf(xv.z * inv); o.w = f2bf(xv.w * inv);
    *(ushort4*)(y + wid * 256 + lane * 4) = o;
}

// ---------------------------------------------------------------------------
// Chunk prep. Outputs: u (f32), w16 [blk][32][256] bf16, kT16 [blk][256][32]
// bf16, al16 [blk][32][32] bf16.
// ---------------------------------------------------------------------------
__global__ __launch_bounds__(256) void chunk_prep(
    const ushort* __restrict__ qn, const ushort* __restrict__ kn,
    const float* __restrict__ v, const float* __restrict__ beta,
    float* __restrict__ u, ushort* __restrict__ w16,
    ushort* __restrict__ kT16, ushort* __restrict__ al16)
{
    __shared__ float kb_s[32 * 256];
    __shared__ float bufB[32 * 256];
    __shared__ float Ms[32 * 33];
    __shared__ float Rs[32 * 33];
    __shared__ float bet[32];
    const int blk = blockIdx.x;
    const int n = blk & 63;
    const int bh = blk >> 6;
    const int h = bh & 3;
    const int b = bh >> 2;
    const int tid = threadIdx.x;
    const long lbase = (long)b * 2048 + n * 32;

    if (tid < 32) bet[tid] = beta[(lbase + tid) * 4 + h];
    __syncthreads();
    for (int e = tid; e < 8192; e += 256) {
        const int c = e >> 8, dd = e & 255;
        const float kv = bf2f(kn[(lbase + c) * 1024 + h * 256 + dd]);
        bufB[dd * 32 + c] = kv;
        kb_s[c * 256 + dd] = kv * bet[c];
    }
    __syncthreads();
    for (int e = tid; e < 8192; e += 256)
        kT16[(long)blk * 8192 + e] = f2bf(bufB[e]);

    const int j = tid & 31, i0 = tid >> 5;
    {
        float m4[4] = {0.f, 0.f, 0.f, 0.f};
        for (int dd = 0; dd < 256; ++dd) {
            const float kt = bufB[dd * 32 + j];
            #pragma unroll
            for (int ii = 0; ii < 4; ++ii) m4[ii] += kb_s[(i0 + 8 * ii) * 256 + dd] * kt;
        }
        #pragma unroll
        for (int ii = 0; ii < 4; ++ii) {
            const int i = i0 + 8 * ii;
            const float mv = (i > j) ? -m4[ii] : 0.f;
            Ms[i * 33 + j] = mv;
            Rs[i * 33 + j] = mv + ((i == j) ? 1.f : 0.f);
        }
    }
    {
        float a4[4] = {0.f, 0.f, 0.f, 0.f};
        for (int dd = 0; dd < 256; ++dd) {
            const float kt = bufB[dd * 32 + j];
            #pragma unroll
            for (int ii = 0; ii < 4; ++ii)
                a4[ii] += bf2f(qn[(lbase + (i0 + 8 * ii)) * 1024 + h * 256 + dd]) * kt;
        }
        #pragma unroll
        for (int ii = 0; ii < 4; ++ii) {
            const int i = i0 + 8 * ii;
            al16[(long)blk * 1024 + i * 32 + j] = f2bf((i >= j) ? a4[ii] : 0.f);
        }
    }
    __syncthreads();
    for (int it = 0; it < 4; ++it) {
        float p4[4] = {0.f, 0.f, 0.f, 0.f};
        for (int kk = 0; kk < 32; ++kk) {
            const float pb = Ms[kk * 33 + j];
            #pragma unroll
            for (int ii = 0; ii < 4; ++ii) p4[ii] += Ms[(i0 + 8 * ii) * 33 + kk] * pb;
        }
        __syncthreads();
        #pragma unroll
        for (int ii = 0; ii < 4; ++ii) Ms[(i0 + 8 * ii) * 33 + j] = p4[ii];
        __syncthreads();
        float r4[4] = {0.f, 0.f, 0.f, 0.f};
        for (int kk = 0; kk < 32; ++kk) {
            const float pb = Ms[kk * 33 + j];
            #pragma unroll
            for (int ii = 0; ii < 4; ++ii) r4[ii] += Rs[(i0 + 8 * ii) * 33 + kk] * pb;
        }
        __syncthreads();
        #pragma unroll
        for (int ii = 0; ii < 4; ++ii) Rs[(i0 + 8 * ii) * 33 + j] += r4[ii];
        __syncthreads();
    }
    for (int e = tid; e < 8192; e += 256) {
        const int c = e >> 8, dd = e & 255;
        bufB[c * 256 + dd] = v[(lbase + c) * 1024 + h * 256 + dd] * bet[c];
    }
    __syncthreads();
    {
        const int dd = tid;
        float accU[32], accW[32];
        #pragma unroll
        for (int r = 0; r < 32; ++r) { accU[r] = 0.f; accW[r] = 0.f; }
        for (int kk = 0; kk < 32; ++kk) {
            const float vv = bufB[kk * 256 + dd];
            const float bb = kb_s[kk * 256 + dd];
            #pragma unroll
            for (int r = 0; r < 32; ++r) {
                const float rr = Rs[r * 33 + kk];
                accU[r] += rr * vv;
                accW[r] += rr * bb;
            }
        }
        const long base = (long)blk * 32;
        #pragma unroll
        for (int r = 0; r < 32; ++r) {
            u  [(base + r) * 256 + dd] = accU[r];
            w16[(base + r) * 256 + dd] = f2bf(accW[r]);
        }
    }
}

// ---------------------------------------------------------------------------
// MFMA delta scan: 64 blocks x 4 waves (256 thr). Block = (bh = blk&15,
// quarter = blk>>4); all quarters of a bh share XCD blk&7. Wave wv owns
// slice sl = quarter*4 + wv (16 dv-cols). Shared double-buffered LDS staging
// of w/kT/al (slice-independent), cooperatively loaded via global_load_lds
// split across waves; per-wave counted s_waitcnt vmcnt (chunk n+1 loads stay
// in flight) + raw s_barrier (no implicit vmcnt(0) drain). q (slice-indep,
// L1-shared) and u (slice-private) read direct from global. Per chunk
// (math identical to the verified round-3..6 scan):
//   u' = u - w@S ; o = q@S + aloc@u' ; S += kT@u'
// W staged with XOR swizzle elem^=((row&7)<<3) (inverse-swizzled source,
// swizzled read). LDS = 68KB staging + 33KB Sb + 5KB Ub = 106KB.
// ---------------------------------------------------------------------------
__global__ __launch_bounds__(256) void delta_scan_mfma(
    const ushort* __restrict__ q16, const ushort* __restrict__ kT16,
    const ushort* __restrict__ w16, const float* __restrict__ u,
    const ushort* __restrict__ al16, float* __restrict__ dt)
{
    // staging layout (elem offsets): W 0 | KT 8192 | AL 16384
    __shared__ __align__(16) ushort Stg[2][17408];
    __shared__ __align__(16) ushort Sb[4][16 * 264];
    __shared__ __align__(16) ushort Ub[4][16 * 40];
    const int blk = blockIdx.x;
    const int bh = blk & 15;
    const int qtr = blk >> 4;
    const int tid = threadIdx.x;
    const int wv = tid >> 6;
    const int lane = tid & 63;
    const int sl = qtr * 4 + wv;
    const int h = bh & 3;
    const int b = bh >> 2;
    const int v0 = sl * 16;
    const int col = lane & 15;
    const int grp = lane >> 4;
    const int l5 = lane & 31;
    const int lh = lane >> 5;

    f32x4 S[16];
    #pragma unroll
    for (int t = 0; t < 16; ++t) { S[t][0] = 0.f; S[t][1] = 0.f; S[t][2] = 0.f; S[t][3] = 0.f; }
    for (int i = lane; i < 16 * 264; i += 64) Sb[wv][i] = 0;

    const ushort* Wg = w16  + (long)bh * 64 * 8192;
    const ushort* Qg = q16  + ((long)b * 2048) * 1024 + h * 256;
    const ushort* Kg = kT16 + (long)bh * 64 * 8192;
    const ushort* Ag = al16 + (long)bh * 64 * 1024;
    const float*  Ug = u    + (long)bh * 64 * 8192 + grp * 1024 + v0 + col;
    const ushort* qp = Qg + col * 1024 + grp * 8;
    float*        dp = dt   + ((long)b * 2048 + grp * 4) * 1024 + h * 256 + v0 + col;

    // cooperative stage of chunk n into buffer sb: wave wv takes W rows-pairs
    // [4wv,4wv+4), KT blocks [4wv,4wv+4), AL both on wave 0. Counts: wv0=10, else 8.
    auto STAGE = [&](int n, int sb) {
        ushort* dst = &Stg[sb][0];
        const ushort* wsrc = Wg + (long)n * 8192;
        #pragma unroll
        for (int i = 0; i < 4; ++i) {
            const int blkW = wv * 4 + i;
            const int row = 2 * blkW + lh;
            const int key = row & 7;
            __builtin_amdgcn_global_load_lds(
                (const __attribute__((address_space(1))) void*)(wsrc + row * 256 + ((l5 ^ key) << 3)),
                (__attribute__((address_space(3))) void*)(dst + blkW * 512), 16, 0, 0);
        }
        const ushort* ksrc = Kg + (long)n * 8192;
        #pragma unroll
        for (int i = 0; i < 4; ++i) {
            const int j = wv * 4 + i;
            __builtin_amdgcn_global_load_lds(
                (const __attribute__((address_space(1))) void*)(ksrc + j * 512 + lane * 8),
                (__attribute__((address_space(3))) void*)(dst + 8192 + j * 512), 16, 0, 0);
        }
        if (wv == 0) {
            const ushort* asrc = Ag + (long)n * 1024;
            #pragma unroll
            for (int i = 0; i < 2; ++i)
                __builtin_amdgcn_global_load_lds(
                    (const __attribute__((address_space(1))) void*)(asrc + i * 512 + lane * 8),
                    (__attribute__((address_space(3))) void*)(dst + 16384 + i * 512), 16, 0, 0);
        }
    };

    const int xk = (col & 7) << 3;   // read-side swizzle key for W

    STAGE(0, 0);
    for (int n = 0; n < 64; ++n) {
        const int s = n & 1;
        // bar1: all waves finished reading buf[s^1] (iter n-1 compute)
        __builtin_amdgcn_sched_barrier(0);
        __builtin_amdgcn_s_barrier();
        __builtin_amdgcn_sched_barrier(0);
        if (n < 63) {
            STAGE(n + 1, s ^ 1);
            // wait own chunk-n staging loads; leave chunk-n+1 (10 or 8) in flight
            if (wv == 0) asm volatile("s_waitcnt vmcnt(10)" ::: "memory");
            else         asm volatile("s_waitcnt vmcnt(8)"  ::: "memory");
        } else {
            asm volatile("s_waitcnt vmcnt(0)" ::: "memory");
        }
        // bar2: all waves' chunk-n loads landed in buf[s]
        __builtin_amdgcn_sched_barrier(0);
        __builtin_amdgcn_s_barrier();
        __builtin_amdgcn_sched_barrier(0);
        const ushort* Sg = &Stg[s][0];

        // prefetch u for this chunk (8 f32, slice-private)
        float upre[8];
        #pragma unroll
        for (int rt = 0; rt < 2; ++rt)
            #pragma unroll
            for (int r = 0; r < 4; ++r)
                upre[rt * 4 + r] = Ug[(long)n * 8192 + rt * 4096 + r * 256];

        // --- read S B-frags (col-major S in Sb[wv])
        bf16x8 sf[8];
        #pragma unroll
        for (int kb = 0; kb < 8; ++kb)
            sf[kb] = *(const bf16x8*)&Sb[wv][col * 264 + kb * 32 + grp * 8];

        // --- issue q A-frag loads early (consumed in o-phase)
        bf16x8 qf[2][8];
        #pragma unroll
        for (int rt = 0; rt < 2; ++rt)
            #pragma unroll
            for (int kb = 0; kb < 8; ++kb)
                qf[rt][kb] = *(const bf16x8*)(qp + (long)n * 32768 + rt * 16384 + kb * 32);

        // --- u' = u - w@S
        f32x4 up[2];
        #pragma unroll
        for (int rt = 0; rt < 2; ++rt) {
            f32x4 a; a[0] = 0.f; a[1] = 0.f; a[2] = 0.f; a[3] = 0.f;
            #pragma unroll
            for (int kb = 0; kb < 8; ++kb) {
                const int widx = ((rt * 16 + col) << 8) + (((kb << 5) + (grp << 3)) ^ xk);
                const bf16x8 wf = *(const bf16x8*)&Sg[widx];
                a = __builtin_amdgcn_mfma_f32_16x16x32_bf16(wf, sf[kb], a, 0, 0, 0);
            }
            #pragma unroll
            for (int r = 0; r < 4; ++r)
                up[rt][r] = upre[rt * 4 + r] - a[r];
        }
        // --- write u' (bf16, col-major) to Ub[wv]
        #pragma unroll
        for (int rt = 0; rt < 2; ++rt) {
            ushort4 p;
            p.x = f2bf(up[rt][0]); p.y = f2bf(up[rt][1]);
            p.z = f2bf(up[rt][2]); p.w = f2bf(up[rt][3]);
            *(ushort4*)&Ub[wv][col * 40 + rt * 16 + grp * 4] = p;
        }
        const bf16x8 uf = *(const bf16x8*)&Ub[wv][col * 40 + grp * 8];

        // --- o = q@S + aloc@u' ; store to dt
        #pragma unroll
        for (int rt = 0; rt < 2; ++rt) {
            f32x4 a; a[0] = 0.f; a[1] = 0.f; a[2] = 0.f; a[3] = 0.f;
            #pragma unroll
            for (int kb = 0; kb < 8; ++kb)
                a = __builtin_amdgcn_mfma_f32_16x16x32_bf16(qf[rt][kb], sf[kb], a, 0, 0, 0);
            const bf16x8 alf = *(const bf16x8*)&Sg[16384 + rt * 512 + col * 32 + grp * 8];
            a = __builtin_amdgcn_mfma_f32_16x16x32_bf16(alf, uf, a, 0, 0, 0);
            #pragma unroll
            for (int r = 0; r < 4; ++r)
                dp[(long)n * 32768 + rt * 16384 + r * 1024] = a[r];
        }

        // --- S += kT @ u'
        #pragma unroll
        for (int t = 0; t < 16; ++t) {
            const bf16x8 kf = *(const bf16x8*)&Sg[8192 + t * 512 + col * 32 + grp * 8];
            S[t] = __builtin_amdgcn_mfma_f32_16x16x32_bf16(kf, uf, S[t], 0, 0, 0);
        }

        // --- write S (bf16, col-major) to Sb[wv] for next chunk
        #pragma unroll
        for (int t = 0; t < 16; ++t) {
            ushort4 p;
            p.x = f2bf(S[t][0]); p.y = f2bf(S[t][1]);
            p.z = f2bf(S[t][2]); p.w = f2bf(S[t][3]);
            *(ushort4*)&Sb[wv][col * 264 + t * 16 + grp * 4] = p;
        }
    }
}

// ---------------------------------------------------------------------------
// Multiscale causal depthwise conv -> bf16 out. Flat-index identity:
// y[(b*2048+l)*3072 + sc*1024 + c]. Thread = (b, c, 8-l window).
// ---------------------------------------------------------------------------
__global__ __launch_bounds__(256) void ms_conv(const float* __restrict__ v,
    const float* __restrict__ w3, const float* __restrict__ w15,
    const float* __restrict__ w31, ushort* __restrict__ y)
{
    const int bid = blockIdx.x;
    const int b = bid >> 10;
    const int oct = (bid >> 2) & 255;
    const int c = ((bid & 3) << 8) + threadIdx.x;
    const int l0 = oct << 3;
    const float* vb = v + ((long)b * 2048) * 1024 + c;
    ushort* yb = y + ((long)b * 2048) * 3072 + c;

    float win[38];
    #pragma unroll
    for (int t = 0; t < 38; ++t) {
        const int ll = l0 - 30 + t;
        win[t] = (ll >= 0) ? vb[(long)ll * 1024] : 0.f;
    }
    {
        float W[31];
        #pragma unroll
        for (int t = 0; t < 31; ++t) W[t] = w31[c * 31 + t];
        #pragma unroll
        for (int j = 0; j < 8; ++j) {
            float s = 0.f;
            #pragma unroll
            for (int t = 0; t < 31; ++t) s += win[j + t] * W[t];
            yb[(long)(l0 + j) * 3072 + 2048] = f2bf(s);
        }
    }
    {
        float W[15];
        #pragma unroll
        for (int t = 0; t < 15; ++t) W[t] = w15[c * 15 + t];
        #pragma unroll
        for (int j = 0; j < 8; ++j) {
            float s = 0.f;
            #pragma unroll
            for (int t = 0; t < 15; ++t) s += win[j + 16 + t] * W[t];
            yb[(long)(l0 + j) * 3072 + 1024] = f2bf(s);
        }
    }
    {
        float W[3];
        #pragma unroll
        for (int t = 0; t < 3; ++t) W[t] = w3[c * 3 + t];
        #pragma unroll
        for (int j = 0; j < 8; ++j) {
            float s = 0.f;
            #pragma unroll
            for (int t = 0; t < 3; ++t) s += win[j + 28 + t] * W[t];
            yb[(long)(l0 + j) * 3072] = f2bf(s);
        }
    }
}

// ---------------------------------------------------------------------------
// bn features: bn[bl,12] = [mean|ms| | mean|dt| | mean|v|] per head.
// ---------------------------------------------------------------------------
__global__ __launch_bounds__(256) void build_bn(const float* __restrict__ ms,
    const float* __restrict__ dt, const float* __restrict__ v,
    float* __restrict__ bn)
{
    const int bl = blockIdx.x, tid = threadIdx.x;
    const long rb = (long)bl * 1024;
    const int wid = tid >> 6, lane = tid & 63;
    const long base = rb + wid * 256 + lane * 4;
    float* g = bn + (long)bl * 12;
    float4 a;
    float s;
    a = *(const float4*)(ms + base);
    s = fabsf(a.x) + fabsf(a.y) + fabsf(a.z) + fabsf(a.w);
    for (int off = 32; off > 0; off >>= 1) s += __shfl_down(s, off);
    if (lane == 0) g[wid] = s * (1.f / 256.f);
    a = *(const float4*)(dt + base);
    s = fabsf(a.x) + fabsf(a.y) + fabsf(a.z) + fabsf(a.w);
    for (int off = 32; off > 0; off >>= 1) s += __shfl_down(s, off);
    if (lane == 0) g[4 + wid] = s * (1.f / 256.f);
    a = *(const float4*)(v + base);
    s = fabsf(a.x) + fabsf(a.y) + fabsf(a.z) + fabsf(a.w);
    for (int off = 32; off > 0; off >>= 1) s += __shfl_down(s, off);
    if (lane == 0) g[8 + wid] = s * (1.f / 256.f);
}

// ---------------------------------------------------------------------------
// Blend + per-head RMSNorm * o_norm_w -> bf16 out.
// ---------------------------------------------------------------------------
__global__ __launch_bounds__(256) void blend_rms(const float* __restrict__ ms,
    const float* __restrict__ dt, const float* __restrict__ v,
    const float* __restrict__ wts, const float* __restrict__ onw,
    ushort* __restrict__ o)
{
    const int bl = blockIdx.x, tid = threadIdx.x;
    const int wid = tid >> 6, lane = tid & 63;
    const long base = (long)bl * 1024 + wid * 256 + lane * 4;
    const float* wr = wts + (long)bl * 12 + wid * 3;
    const float w0 = wr[0], w1 = wr[1], w2 = wr[2];
    const float4 m = *(const float4*)(ms + base);
    const float4 d = *(const float4*)(dt + base);
    const float4 x = *(const float4*)(v + base);
    float4 ov;
    ov.x = w0 * m.x + w1 * d.x + w2 * x.x;
    ov.y = w0 * m.y + w1 * d.y + w2 * x.y;
    ov.z = w0 * m.z + w1 * d.z + w2 * x.z;
    ov.w = w0 * m.w + w1 * d.w + w2 * x.w;
    float ss = ov.x * ov.x + ov.y * ov.y + ov.z * ov.z + ov.w * ov.w;
    for (int off = 32; off > 0; off >>= 1) ss += __shfl_down(ss, off);
    ss = __shfl(ss, 0);
    const float inv = rsqrtf(ss * (1.f / 256.f) + 1e-5f);
    const float4 nw = *(const float4*)(onw + lane * 4);
    ushort4 ob;
    ob.x = f2bf(ov.x * inv * nw.x); ob.y = f2bf(ov.y * inv * nw.y);
    ob.z = f2bf(ov.z * inv * nw.z); ob.w = f2bf(ov.w * inv * nw.w);
    *(ushort4*)(o + base) = ob;
}

// ---------------------------------------------------------------------------
extern "C" void kernel_launch(void* const* d_in, const int* in_sizes, int n_in,
                              void* d_out, int out_size, void* d_ws, size_t ws_size,
                              hipStream_t stream)
{
    (void)in_sizes; (void)n_in; (void)out_size; (void)ws_size;
    const float* hid   = (const float*)d_in[0];
    const float* Wq    = (const float*)d_in[1];
    const float* Wk    = (const float*)d_in[2];
    const float* Wv    = (const float*)d_in[3];
    const float* Wb    = (const float*)d_in[4];
    const float* cq    = (const float*)d_in[5];
    const float* ck    = (const float*)d_in[6];
    const float* cv    = (const float*)d_in[7];
    const float* w3    = (const float*)d_in[8];
    const float* w15   = (const float*)d_in[9];
    const float* w31   = (const float*)d_in[10];
    const float* kmix  = (const float*)d_in[11];
    const float* cmix  = (const float*)d_in[12];
    const float* fw1   = (const float*)d_in[13];
    const float* fb1   = (const float*)d_in[14];
    const float* fw2   = (const float*)d_in[15];
    const float* fb2   = (const float*)d_in[16];
    const float* onw   = (const float*)d_in[17];
    const float* Wo    = (const float*)d_in[18];
    float* out = (float*)d_out;

    // ---- workspace carve (peak ~195 MiB) ----
    const size_t MiB = 1024 * 1024;
    char* W = (char*)d_ws;
    float*  s0    = (float*)(W);              // qlin -> u(f32) -> yms[lo] -> hdn16
    char*   s1c   = W + 32 * MiB;             // qtmp -> w16|kT16 -> yms[hi] -> msout
    float*  s1    = (float*)s1c;
    float*  s2    = (float*)(W + 64 * MiB);   // vlin -> dt
    char*   s3    = W + 96 * MiB;             // q16|k16 -> mix16|ofin16
    float*  s4    = (float*)(W + 128 * MiB);  // v (long-lived)
    ushort* hid16 = (ushort*)(W + 160 * MiB);
    ushort* WqT   = (ushort*)(W + 176 * MiB);
    ushort* WkT   = WqT   + 1024 * 1024;
    ushort* WvT   = WkT   + 1024 * 1024;
    ushort* cmixT = WvT   + 1024 * 1024;
    ushort* WoT   = cmixT + 1024 * 1024;
    ushort* fw1T  = WoT   + 1024 * 1024;      // [2048][1024]
    ushort* kmixT = fw1T  + 2048 * 1024;      // [256][768]
    float*  beta  = (float*)(W + 191 * MiB);  // 128 KB
    ushort* al16  = (ushort*)(W + 191 * MiB + 128 * 1024);  // 2 MiB
    float*  bnf   = (float*)(W + 193 * MiB + 128 * 1024);   // 384 KB
    float*  wts   = bnf + 98304;                            // 384 KB

    ushort* q16    = (ushort*)s3;
    ushort* k16    = (ushort*)(s3 + 16 * MiB);
    ushort* mix16  = q16;
    ushort* ofin16 = k16;
    ushort* yms16  = (ushort*)s0;             // 48 MiB spans s0+s1
    ushort* hdn16  = (ushort*)s0;
    float*  qlin = s0; float* qtmp = s1;
    float*  u = s0;
    ushort* w16  = (ushort*)s1c;              // 16 MiB
    ushort* kT16 = (ushort*)(s1c + 16 * MiB); // 16 MiB
    float*  dt = s2; float* v = s4; float* msout = s1;

    const dim3 T256(256);
    // 0. casts / weight transposes
    cast_bf16<<<8192, T256, 0, stream>>>(hid, hid16);
    transpose_cast<<<dim3(32, 32), T256, 0, stream>>>(Wq, WqT, 1024, 1024);
    transpose_cast<<<dim3(32, 32), T256, 0, stream>>>(Wk, WkT, 1024, 1024);
    transpose_cast<<<dim3(32, 32), T256, 0, stream>>>(Wv, WvT, 1024, 1024);
    transpose_cast<<<dim3(32, 32), T256, 0, stream>>>(cmix, cmixT, 1024, 1024);
    transpose_cast<<<dim3(32, 32), T256, 0, stream>>>(Wo, WoT, 1024, 1024);
    transpose_cast<<<dim3(64, 32), T256, 0, stream>>>(fw1, fw1T, 1024, 2048);
    transpose_cast<<<dim3(8, 24), T256, 0, stream>>>(kmix, kmixT, 768, 256);
    // 1. q pipeline
    gemm_mfma<0><<<dim3(8, 64), T256, 0, stream>>>(hid16, WqT, nullptr, nullptr, nullptr, qlin, 8192, 1024, 1024);
    conv4_silu<<<32768, T256, 0, stream>>>(qlin, cq, qtmp);
    l2norm_bf16<<<8192, T256, 0, stream>>>(qtmp, q16);
    // 2. k pipeline
    gemm_mfma<0><<<dim3(8, 64), T256, 0, stream>>>(hid16, WkT, nullptr, nullptr, nullptr, qlin, 8192, 1024, 1024);
    conv4_silu<<<32768, T256, 0, stream>>>(qlin, ck, qtmp);
    l2norm_bf16<<<8192, T256, 0, stream>>>(qtmp, k16);
    // 3. v pipeline
    gemm_mfma<0><<<dim3(8, 64), T256, 0, stream>>>(hid16, WvT, nullptr, nullptr, nullptr, qlin, 8192, 1024, 1024);
    conv4_silu<<<32768, T256, 0, stream>>>(qlin, cv, v);
    // 4. beta
    gemm_smallN<4, 0><<<8192, T256, 0, stream>>>(hid, Wb, nullptr, beta, 1024);
    // 5. delta rule: prep + MFMA scan (4-wave shared-staged blocks)
    chunk_prep<<<1024, T256, 0, stream>>>(q16, k16, v, beta, u, w16, kT16, al16);
    delta_scan_mfma<<<64, T256, 0, stream>>>(q16, kT16, w16, u, al16, dt);
    // 6. multiscale conv branch
    ms_conv<<<4096, T256, 0, stream>>>(v, w3, w15, w31, yms16);
    gemm_mfma<1><<<dim3(2, 256), T256, 0, stream>>>(yms16, kmixT, nullptr, nullptr, nullptr, mix16, 32768, 256, 768);
    gemm_mfma<0><<<dim3(8, 64), T256, 0, stream>>>(mix16, cmixT, nullptr, nullptr, nullptr, msout, 8192, 1024, 1024);
    // 7. fusion gate
    build_bn<<<8192, T256, 0, stream>>>(msout, dt, v, bnf);
    gemm_mfma<3><<<dim3(16, 64), T256, 0, stream>>>(hid16, fw1T, fb1, bnf, fw1 + 1024L * 2048, hdn16, 8192, 2048, 1024);
    gemm_smallN<12, 1><<<8192, T256, 0, stream>>>(hdn16, fw2, fb2, wts, 2048);
    // 8. blend + output projection
    blend_rms<<<8192, T256, 0, stream>>>(msout, dt, v, wts, onw, ofin16);
    gemm_mfma<0><<<dim3(8, 64), T256, 0, stream>>>(ofin16, WoT, nullptr, nullptr, nullptr, out, 8192, 1024, 1024);
}

// Round 8
// 837.070 us; speedup vs baseline: 1.1186x; 1.1186x over previous
//
#include <hip/hip_runtime.h>
#include <math.h>

// Problem constants: B=4, L=2048, D=1024, H=4, dk=dv=256, CHUNK=32, NCHUNK=64
// bf16 MFMA for all large GEMMs AND the delta-rule scan (LDS-staged, dbuf,
// 1-wave blocks, u-prefetch + counted vmcnt).

typedef __attribute__((ext_vector_type(8))) __bf16 bf16x8;
typedef __attribute__((ext_vector_type(4))) float f32x4;

__device__ inline ushort f2bf(float f) {
    union { float f; unsigned u; } x; x.f = f;
    unsigned u = x.u;
    u += 0x7fffu + ((u >> 16) & 1u);
    return (ushort)(u >> 16);
}
__device__ inline float bf2f(ushort h) {
    union { unsigned u; float f; } x; x.u = ((unsigned)h) << 16;
    return x.f;
}
__device__ inline float ldf(float v) { return v; }
__device__ inline float ldf(ushort v) { return bf2f(v); }

// ---------------------------------------------------------------------------
// bf16 MFMA GEMM: C[M,N] = A[M,K] @ BT[N,K]^T. 128x128 tile, BK=64 (split-half
// LDS layout [2][128][32] keeps the BK=32 bank profile; halves barrier count).
// 4 waves. EPI 0: f32 out. 1: bf16 out. 3: bias+rank12+gelu, bf16 out.
// Requires K % 64 == 0 (all call sites: 1024, 768).
// ---------------------------------------------------------------------------
template<int EPI>
__global__ __launch_bounds__(256) void gemm_mfma(
    const ushort* __restrict__ A, const ushort* __restrict__ BT,
    const float* __restrict__ bias, const float* __restrict__ extA,
    const float* __restrict__ extB, void* __restrict__ Cout,
    int M, int N, int K)
{
    __shared__ ushort As[2][128 * 32];
    __shared__ ushort Bs[2][128 * 32];
    __shared__ float bns[(EPI >= 2) ? 128 * 13 : 1];
    __shared__ float exb[(EPI >= 2) ? 12 * 128 : 1];
    const int tid = threadIdx.x;
    const int row0 = blockIdx.y * 128, col0 = blockIdx.x * 128;
    const int lane = tid & 63, wave = tid >> 6;
    const int wr = (wave >> 1) * 64, wc = (wave & 1) * 64;

    if (EPI >= 2) {
        for (int e = tid; e < 128 * 12; e += 256)
            bns[(e / 12) * 13 + (e % 12)] = extA[(long)(row0 + e / 12) * 12 + e % 12];
        for (int e = tid; e < 12 * 128; e += 256)
            exb[e] = extB[(long)(e >> 7) * N + col0 + (e & 127)];
    }

    f32x4 acc[4][4];
    #pragma unroll
    for (int m = 0; m < 4; ++m)
        #pragma unroll
        for (int n = 0; n < 4; ++n) {
            acc[m][n][0] = 0.f; acc[m][n][1] = 0.f;
            acc[m][n][2] = 0.f; acc[m][n][3] = 0.f;
        }

    const int rA = lane & 15;
    const int ko = (lane >> 4) * 8;
    const int srow = tid >> 2;          // 0..63
    const int skk = (tid & 3) * 8;

    for (int k0 = 0; k0 < K; k0 += 64) {
        #pragma unroll
        for (int hf = 0; hf < 2; ++hf) {
            #pragma unroll
            for (int i = 0; i < 2; ++i) {
                const long ga = (long)(row0 + i * 64 + srow) * K + k0 + hf * 32 + skk;
                __builtin_amdgcn_global_load_lds(
                    (const __attribute__((address_space(1))) void*)(A + ga),
                    (__attribute__((address_space(3))) void*)(&As[hf][0] + i * 2048 + wave * 512),
                    16, 0, 0);
                const long gb = (long)(col0 + i * 64 + srow) * K + k0 + hf * 32 + skk;
                __builtin_amdgcn_global_load_lds(
                    (const __attribute__((address_space(1))) void*)(BT + gb),
                    (__attribute__((address_space(3))) void*)(&Bs[hf][0] + i * 2048 + wave * 512),
                    16, 0, 0);
            }
        }
        __syncthreads();
        #pragma unroll
        for (int hf = 0; hf < 2; ++hf) {
            bf16x8 af[4], bfr[4];
            #pragma unroll
            for (int m = 0; m < 4; ++m)
                af[m] = *(const bf16x8*)(&As[hf][0] + (wr + m * 16 + rA) * 32 + ko);
            #pragma unroll
            for (int n = 0; n < 4; ++n)
                bfr[n] = *(const bf16x8*)(&Bs[hf][0] + (wc + n * 16 + rA) * 32 + ko);
            #pragma unroll
            for (int m = 0; m < 4; ++m)
                #pragma unroll
                for (int n = 0; n < 4; ++n)
                    acc[m][n] = __builtin_amdgcn_mfma_f32_16x16x32_bf16(af[m], bfr[n], acc[m][n], 0, 0, 0);
        }
        __syncthreads();
    }

    const int crow = (lane >> 4) * 4;
    const int ccol = lane & 15;
    #pragma unroll
    for (int m = 0; m < 4; ++m) {
        #pragma unroll
        for (int n = 0; n < 4; ++n) {
            #pragma unroll
            for (int r = 0; r < 4; ++r) {
                const int rl = wr + m * 16 + crow + r;
                const int cl = wc + n * 16 + ccol;
                float vv = acc[m][n][r];
                if (EPI >= 2) {
                    vv += bias[col0 + cl];
                    #pragma unroll
                    for (int j = 0; j < 12; ++j) vv += bns[rl * 13 + j] * exb[j * 128 + cl];
                    vv = 0.5f * vv * (1.f + erff(vv * 0.70710678118654752f));
                }
                const long off = (long)(row0 + rl) * N + col0 + cl;
                if (EPI == 0) ((float*)Cout)[off] = vv;
                else ((ushort*)Cout)[off] = f2bf(vv);
            }
        }
    }
}

// ---------------------------------------------------------------------------
// Transpose + cast to bf16: W[K][N] f32 -> WT[N][K] bf16.
// ---------------------------------------------------------------------------
__global__ __launch_bounds__(256) void transpose_cast(const float* __restrict__ W,
    ushort* __restrict__ WT, int K, int N)
{
    __shared__ float t[32][33];
    const int k0 = blockIdx.y * 32, n0 = blockIdx.x * 32;
    const int c = threadIdx.x & 31, r8 = threadIdx.x >> 5;
    #pragma unroll
    for (int rr = 0; rr < 4; ++rr) {
        const int r = r8 + rr * 8;
        t[r][c] = W[(long)(k0 + r) * N + n0 + c];
    }
    __syncthreads();
    #pragma unroll
    for (int rr = 0; rr < 4; ++rr) {
        const int r = r8 + rr * 8;
        WT[(long)(n0 + r) * K + k0 + c] = f2bf(t[c][r]);
    }
}

__global__ __launch_bounds__(256) void cast_bf16(const float* __restrict__ x,
    ushort* __restrict__ y)
{
    const long i = ((long)blockIdx.x * 256 + threadIdx.x) * 4;
    const float4 v = *(const float4*)(x + i);
    ushort4 o;
    o.x = f2bf(v.x); o.y = f2bf(v.y); o.z = f2bf(v.z); o.w = f2bf(v.w);
    *(ushort4*)(y + i) = o;
}

// ---------------------------------------------------------------------------
// Small-N GEMM. MODE 0: sigmoid. MODE 1: +bias, per-head softmax over triples.
// ---------------------------------------------------------------------------
template<int NOUT, int MODE, typename TA>
__global__ __launch_bounds__(256) void gemm_smallN(const TA* __restrict__ A,
    const float* __restrict__ Bm, const float* __restrict__ bias,
    float* __restrict__ Cm, int K)
{
    __shared__ float part[4][NOUT];
    __shared__ float sm[NOUT];
    const int m = blockIdx.x, tid = threadIdx.x;
    const TA* ar = A + (long)m * K;
    float acc[NOUT];
    #pragma unroll
    for (int j = 0; j < NOUT; ++j) acc[j] = 0.f;
    for (int k = tid; k < K; k += 256) {
        const float a = ldf(ar[k]);
        #pragma unroll
        for (int j = 0; j < NOUT; ++j) acc[j] += a * Bm[(long)k * NOUT + j];
    }
    #pragma unroll
    for (int j = 0; j < NOUT; ++j)
        for (int off = 32; off > 0; off >>= 1) acc[j] += __shfl_down(acc[j], off);
    const int wid = tid >> 6, lane = tid & 63;
    if (lane == 0) {
        #pragma unroll
        for (int j = 0; j < NOUT; ++j) part[wid][j] = acc[j];
    }
    __syncthreads();
    if (tid < NOUT) {
        float s = part[0][tid] + part[1][tid] + part[2][tid] + part[3][tid];
        if (MODE == 0) {
            Cm[(long)m * NOUT + tid] = 1.f / (1.f + expf(-s));
        } else {
            sm[tid] = s + bias[tid];
        }
    }
    if (MODE == 1) {
        __syncthreads();
        if (tid < NOUT) {
            const int hh = tid / 3, r = tid - hh * 3;
            const float a0 = sm[hh * 3], a1 = sm[hh * 3 + 1], a2 = sm[hh * 3 + 2];
            const float mx = fmaxf(a0, fmaxf(a1, a2));
            const float e0 = expf(a0 - mx), e1 = expf(a1 - mx), e2 = expf(a2 - mx);
            const float mine = (r == 0) ? e0 : ((r == 1) ? e1 : e2);
            Cm[(long)m * NOUT + tid] = mine / (e0 + e1 + e2);
        }
    }
}

// ---------------------------------------------------------------------------
// Depthwise causal conv (k=4) + SiLU, fp32 -> fp32.
// ---------------------------------------------------------------------------
__global__ __launch_bounds__(256) void conv4_silu(const float* __restrict__ x,
    const float* __restrict__ wc, float* __restrict__ y)
{
    const long idx = (long)blockIdx.x * 256 + threadIdx.x;
    const int c = (int)(idx & 1023);
    const long bl = idx >> 10;
    const int l = (int)(bl & 2047);
    const long b = bl >> 11;
    const float* xp = x + b * 2048 * 1024 + c;
    const float* wp = wc + c * 4;
    float s = 0.f;
    #pragma unroll
    for (int t = 0; t < 4; ++t) {
        const int ll = l - 3 + t;
        if (ll >= 0) s += xp[(long)ll * 1024] * wp[t];
    }
    y[idx] = s / (1.f + expf(-s));
}

// ---------------------------------------------------------------------------
// l2 normalize rows of 256 (fp32 in), write bf16.
// ---------------------------------------------------------------------------
__global__ __launch_bounds__(256) void l2norm_bf16(const float* __restrict__ x,
    ushort* __restrict__ y)
{
    const long wid = ((long)blockIdx.x * 256 + threadIdx.x) >> 6;
    const int lane = threadIdx.x & 63;
    const float4 xv = *(const float4*)(x + wid * 256 + lane * 4);
    float ss = xv.x * xv.x + xv.y * xv.y + xv.z * xv.z + xv.w * xv.w;
    for (int off = 32; off > 0; off >>= 1) ss += __shfl_down(ss, off);
    ss = __shfl(ss, 0);
    const float inv = rsqrtf(ss + 1e-6f);
    ushort4 o;
    o.x = f2bf(xv.x * inv); o.y = f2bf(xv.y * inv);
    o.z = f2bf(xv.z * inv); o.w = f2bf(xv.w * inv);
    *(ushort4*)(y + wid * 256 + lane * 4) = o;
}

// ---------------------------------------------------------------------------
// Chunk prep. Outputs: u (f32), w16 [blk][32][256] bf16, kT16 [blk][256][32]
// bf16, al16 [blk][32][32] bf16.
// ---------------------------------------------------------------------------
__global__ __launch_bounds__(256) void chunk_prep(
    const ushort* __restrict__ qn, const ushort* __restrict__ kn,
    const float* __restrict__ v, const float* __restrict__ beta,
    float* __restrict__ u, ushort* __restrict__ w16,
    ushort* __restrict__ kT16, ushort* __restrict__ al16)
{
    __shared__ float kb_s[32 * 256];
    __shared__ float bufB[32 * 256];
    __shared__ float Ms[32 * 33];
    __shared__ float Rs[32 * 33];
    __shared__ float bet[32];
    const int blk = blockIdx.x;
    const int n = blk & 63;
    const int bh = blk >> 6;
    const int h = bh & 3;
    const int b = bh >> 2;
    const int tid = threadIdx.x;
    const long lbase = (long)b * 2048 + n * 32;

    if (tid < 32) bet[tid] = beta[(lbase + tid) * 4 + h];
    __syncthreads();
    for (int e = tid; e < 8192; e += 256) {
        const int c = e >> 8, dd = e & 255;
        const float kv = bf2f(kn[(lbase + c) * 1024 + h * 256 + dd]);
        bufB[dd * 32 + c] = kv;
        kb_s[c * 256 + dd] = kv * bet[c];
    }
    __syncthreads();
    for (int e = tid; e < 8192; e += 256)
        kT16[(long)blk * 8192 + e] = f2bf(bufB[e]);

    const int j = tid & 31, i0 = tid >> 5;
    {
        float m4[4] = {0.f, 0.f, 0.f, 0.f};
        for (int dd = 0; dd < 256; ++dd) {
            const float kt = bufB[dd * 32 + j];
            #pragma unroll
            for (int ii = 0; ii < 4; ++ii) m4[ii] += kb_s[(i0 + 8 * ii) * 256 + dd] * kt;
        }
        #pragma unroll
        for (int ii = 0; ii < 4; ++ii) {
            const int i = i0 + 8 * ii;
            const float mv = (i > j) ? -m4[ii] : 0.f;
            Ms[i * 33 + j] = mv;
            Rs[i * 33 + j] = mv + ((i == j) ? 1.f : 0.f);
        }
    }
    {
        float a4[4] = {0.f, 0.f, 0.f, 0.f};
        for (int dd = 0; dd < 256; ++dd) {
            const float kt = bufB[dd * 32 + j];
            #pragma unroll
            for (int ii = 0; ii < 4; ++ii)
                a4[ii] += bf2f(qn[(lbase + (i0 + 8 * ii)) * 1024 + h * 256 + dd]) * kt;
        }
        #pragma unroll
        for (int ii = 0; ii < 4; ++ii) {
            const int i = i0 + 8 * ii;
            al16[(long)blk * 1024 + i * 32 + j] = f2bf((i >= j) ? a4[ii] : 0.f);
        }
    }
    __syncthreads();
    for (int it = 0; it < 4; ++it) {
        float p4[4] = {0.f, 0.f, 0.f, 0.f};
        for (int kk = 0; kk < 32; ++kk) {
            const float pb = Ms[kk * 33 + j];
            #pragma unroll
            for (int ii = 0; ii < 4; ++ii) p4[ii] += Ms[(i0 + 8 * ii) * 33 + kk] * pb;
        }
        __syncthreads();
        #pragma unroll
        for (int ii = 0; ii < 4; ++ii) Ms[(i0 + 8 * ii) * 33 + j] = p4[ii];
        __syncthreads();
        float r4[4] = {0.f, 0.f, 0.f, 0.f};
        for (int kk = 0; kk < 32; ++kk) {
            const float pb = Ms[kk * 33 + j];
            #pragma unroll
            for (int ii = 0; ii < 4; ++ii) r4[ii] += Rs[(i0 + 8 * ii) * 33 + kk] * pb;
        }
        __syncthreads();
        #pragma unroll
        for (int ii = 0; ii < 4; ++ii) Rs[(i0 + 8 * ii) * 33 + j] += r4[ii];
        __syncthreads();
    }
    for (int e = tid; e < 8192; e += 256) {
        const int c = e >> 8, dd = e & 255;
        bufB[c * 256 + dd] = v[(lbase + c) * 1024 + h * 256 + dd] * bet[c];
    }
    __syncthreads();
    {
        const int dd = tid;
        float accU[32], accW[32];
        #pragma unroll
        for (int r = 0; r < 32; ++r) { accU[r] = 0.f; accW[r] = 0.f; }
        for (int kk = 0; kk < 32; ++kk) {
            const float vv = bufB[kk * 256 + dd];
            const float bb = kb_s[kk * 256 + dd];
            #pragma unroll
            for (int r = 0; r < 32; ++r) {
                const float rr = Rs[r * 33 + kk];
                accU[r] += rr * vv;
                accW[r] += rr * bb;
            }
        }
        const long base = (long)blk * 32;
        #pragma unroll
        for (int r = 0; r < 32; ++r) {
            u  [(base + r) * 256 + dd] = accU[r];
            w16[(base + r) * 256 + dd] = f2bf(accW[r]);
        }
    }
}

// ---------------------------------------------------------------------------
// MFMA delta scan, 256 x 1-wave blocks, LDS double-buffered operand staging
// (round-6 structure) + u prefetched one chunk ahead + counted vmcnt(8):
// issue order per iter = [STAGE(n+1): 50 loads][unext: 8 loads][compute: 8
// stores], all groups pinned by sched_barrier(0). At the loop head the queue
// is [STAGE(n):50][unext:8][stores(n-1):8]; vmcnt(8) retires staging + u
// loads while the previous chunk's dt stores stay in flight.
// Per chunk: u' = u - w@S ; o = q@S + aloc@u' ; S += kT@u'
// w/q staged with XOR swizzle elem ^= ((row&7)<<3) (inverse-swizzled global
// source, swizzled LDS read). LDS = 2*50KB staging + Sb 8.4KB + Ub 1.3KB.
// ---------------------------------------------------------------------------
__global__ __launch_bounds__(64) void delta_scan_mfma(
    const ushort* __restrict__ q16, const ushort* __restrict__ kT16,
    const ushort* __restrict__ w16, const float* __restrict__ u,
    const ushort* __restrict__ al16, float* __restrict__ dt)
{
    // staging layout (elem offsets): W 0 | Q 8192 | KT 16384 | AL 24576
    __shared__ __align__(16) ushort Stg[2][25600];
    __shared__ __align__(16) ushort Sb[16 * 264];
    __shared__ __align__(16) ushort Ub[16 * 40];
    const int blk = blockIdx.x;
    const int bh = blk & 15;
    const int sl = blk >> 4;
    const int h = bh & 3;
    const int b = bh >> 2;
    const int v0 = sl * 16;
    const int lane = threadIdx.x;
    const int col = lane & 15;
    const int grp = lane >> 4;
    const int l5 = lane & 31;
    const int lh = lane >> 5;

    f32x4 S[16];
    #pragma unroll
    for (int t = 0; t < 16; ++t) { S[t][0] = 0.f; S[t][1] = 0.f; S[t][2] = 0.f; S[t][3] = 0.f; }
    for (int i = lane; i < 16 * 264; i += 64) Sb[i] = 0;

    const ushort* Wg = w16  + (long)bh * 64 * 8192;
    const ushort* Qg = q16  + ((long)b * 2048) * 1024 + h * 256;
    const ushort* Kg = kT16 + (long)bh * 64 * 8192;
    const ushort* Ag = al16 + (long)bh * 64 * 1024;
    const float*  Ug = u    + (long)bh * 64 * 8192 + grp * 1024 + v0 + col;
    float*        dp = dt   + ((long)b * 2048 + grp * 4) * 1024 + h * 256 + v0 + col;

    // stage chunk n into buffer s (50 global_load_lds)
    auto STAGE = [&](int n, int s) {
        ushort* dst = &Stg[s][0];
        const ushort* wsrc = Wg + (long)n * 8192;
        #pragma unroll
        for (int i = 0; i < 16; ++i) {
            const int row = 2 * i + lh;
            const int key = row & 7;
            __builtin_amdgcn_global_load_lds(
                (const __attribute__((address_space(1))) void*)(wsrc + row * 256 + ((l5 ^ key) << 3)),
                (__attribute__((address_space(3))) void*)(dst + i * 512), 16, 0, 0);
        }
        #pragma unroll
        for (int i = 0; i < 16; ++i) {
            const int row = 2 * i + lh;
            const int key = row & 7;
            __builtin_amdgcn_global_load_lds(
                (const __attribute__((address_space(1))) void*)(Qg + (long)(n * 32 + row) * 1024 + ((l5 ^ key) << 3)),
                (__attribute__((address_space(3))) void*)(dst + 8192 + i * 512), 16, 0, 0);
        }
        const ushort* ksrc = Kg + (long)n * 8192;
        #pragma unroll
        for (int i = 0; i < 16; ++i)
            __builtin_amdgcn_global_load_lds(
                (const __attribute__((address_space(1))) void*)(ksrc + i * 512 + lane * 8),
                (__attribute__((address_space(3))) void*)(dst + 16384 + i * 512), 16, 0, 0);
        const ushort* asrc = Ag + (long)n * 1024;
        #pragma unroll
        for (int i = 0; i < 2; ++i)
            __builtin_amdgcn_global_load_lds(
                (const __attribute__((address_space(1))) void*)(asrc + i * 512 + lane * 8),
                (__attribute__((address_space(3))) void*)(dst + 24576 + i * 512), 16, 0, 0);
    };

    const int xk = (col & 7) << 3;   // read-side swizzle key for W/Q

    STAGE(0, 0);
    // prologue: u prefetch for chunk 0
    float upre[8];
    #pragma unroll
    for (int rt = 0; rt < 2; ++rt)
        #pragma unroll
        for (int r = 0; r < 4; ++r)
            upre[rt * 4 + r] = Ug[rt * 4096 + r * 256];

    for (int n = 0; n < 64; ++n) {
        const int s = n & 1;
        // retire STAGE(n) + u loads; allow the 8 dt stores of chunk n-1 in flight
        __builtin_amdgcn_sched_barrier(0);
        asm volatile("s_waitcnt vmcnt(8)" ::: "memory");
        __builtin_amdgcn_sched_barrier(0);
        if (n < 63) STAGE(n + 1, s ^ 1);
        __builtin_amdgcn_sched_barrier(0);
        // prefetch u for chunk n+1 (clamped re-load at n=63; value unused)
        float unext[8];
        {
            const long np = (n < 63) ? (long)(n + 1) : 63;
            #pragma unroll
            for (int rt = 0; rt < 2; ++rt)
                #pragma unroll
                for (int r = 0; r < 4; ++r)
                    unext[rt * 4 + r] = Ug[np * 8192 + rt * 4096 + r * 256];
        }
        __builtin_amdgcn_sched_barrier(0);
        const ushort* Sg = &Stg[s][0];

        // --- read S B-frags (col-major S in Sb)
        bf16x8 sf[8];
        #pragma unroll
        for (int kb = 0; kb < 8; ++kb)
            sf[kb] = *(const bf16x8*)&Sb[col * 264 + kb * 32 + grp * 8];

        // --- u' = u - w@S
        f32x4 up[2];
        #pragma unroll
        for (int rt = 0; rt < 2; ++rt) {
            f32x4 a; a[0] = 0.f; a[1] = 0.f; a[2] = 0.f; a[3] = 0.f;
            #pragma unroll
            for (int kb = 0; kb < 8; ++kb) {
                const int widx = ((rt * 16 + col) << 8) + (((kb << 5) + (grp << 3)) ^ xk);
                const bf16x8 wf = *(const bf16x8*)&Sg[widx];
                a = __builtin_amdgcn_mfma_f32_16x16x32_bf16(wf, sf[kb], a, 0, 0, 0);
            }
            #pragma unroll
            for (int r = 0; r < 4; ++r)
                up[rt][r] = upre[rt * 4 + r] - a[r];
        }
        // --- write u' (bf16, col-major) to Ub
        #pragma unroll
        for (int rt = 0; rt < 2; ++rt) {
            ushort4 p;
            p.x = f2bf(up[rt][0]); p.y = f2bf(up[rt][1]);
            p.z = f2bf(up[rt][2]); p.w = f2bf(up[rt][3]);
            *(ushort4*)&Ub[col * 40 + rt * 16 + grp * 4] = p;
        }
        const bf16x8 uf = *(const bf16x8*)&Ub[col * 40 + grp * 8];

        // --- o = q@S + aloc@u' ; store to dt
        #pragma unroll
        for (int rt = 0; rt < 2; ++rt) {
            f32x4 a; a[0] = 0.f; a[1] = 0.f; a[2] = 0.f; a[3] = 0.f;
            #pragma unroll
            for (int kb = 0; kb < 8; ++kb) {
                const int qidx = 8192 + ((rt * 16 + col) << 8) + (((kb << 5) + (grp << 3)) ^ xk);
                const bf16x8 qf = *(const bf16x8*)&Sg[qidx];
                a = __builtin_amdgcn_mfma_f32_16x16x32_bf16(qf, sf[kb], a, 0, 0, 0);
            }
            const bf16x8 alf = *(const bf16x8*)&Sg[24576 + rt * 512 + col * 32 + grp * 8];
            a = __builtin_amdgcn_mfma_f32_16x16x32_bf16(alf, uf, a, 0, 0, 0);
            #pragma unroll
            for (int r = 0; r < 4; ++r)
                dp[(long)n * 32768 + rt * 16384 + r * 1024] = a[r];
        }

        // --- S += kT @ u'
        #pragma unroll
        for (int t = 0; t < 16; ++t) {
            const bf16x8 kf = *(const bf16x8*)&Sg[16384 + t * 512 + col * 32 + grp * 8];
            S[t] = __builtin_amdgcn_mfma_f32_16x16x32_bf16(kf, uf, S[t], 0, 0, 0);
        }

        // --- write S (bf16, col-major) to Sb for next chunk
        #pragma unroll
        for (int t = 0; t < 16; ++t) {
            ushort4 p;
            p.x = f2bf(S[t][0]); p.y = f2bf(S[t][1]);
            p.z = f2bf(S[t][2]); p.w = f2bf(S[t][3]);
            *(ushort4*)&Sb[col * 264 + t * 16 + grp * 4] = p;
        }

        #pragma unroll
        for (int i = 0; i < 8; ++i) upre[i] = unext[i];
    }
}

// ---------------------------------------------------------------------------
// Multiscale causal depthwise conv -> bf16 out. Flat-index identity:
// y[(b*2048+l)*3072 + sc*1024 + c]. Thread = (b, c, 8-l window).
// ---------------------------------------------------------------------------
__global__ __launch_bounds__(256) void ms_conv(const float* __restrict__ v,
    const float* __restrict__ w3, const float* __restrict__ w15,
    const float* __restrict__ w31, ushort* __restrict__ y)
{
    const int bid = blockIdx.x;
    const int b = bid >> 10;
    const int oct = (bid >> 2) & 255;
    const int c = ((bid & 3) << 8) + threadIdx.x;
    const int l0 = oct << 3;
    const float* vb = v + ((long)b * 2048) * 1024 + c;
    ushort* yb = y + ((long)b * 2048) * 3072 + c;

    float win[38];
    #pragma unroll
    for (int t = 0; t < 38; ++t) {
        const int ll = l0 - 30 + t;
        win[t] = (ll >= 0) ? vb[(long)ll * 1024] : 0.f;
    }
    {
        float W[31];
        #pragma unroll
        for (int t = 0; t < 31; ++t) W[t] = w31[c * 31 + t];
        #pragma unroll
        for (int j = 0; j < 8; ++j) {
            float s = 0.f;
            #pragma unroll
            for (int t = 0; t < 31; ++t) s += win[j + t] * W[t];
            yb[(long)(l0 + j) * 3072 + 2048] = f2bf(s);
        }
    }
    {
        float W[15];
        #pragma unroll
        for (int t = 0; t < 15; ++t) W[t] = w15[c * 15 + t];
        #pragma unroll
        for (int j = 0; j < 8; ++j) {
            float s = 0.f;
            #pragma unroll
            for (int t = 0; t < 15; ++t) s += win[j + 16 + t] * W[t];
            yb[(long)(l0 + j) * 3072 + 1024] = f2bf(s);
        }
    }
    {
        float W[3];
        #pragma unroll
        for (int t = 0; t < 3; ++t) W[t] = w3[c * 3 + t];
        #pragma unroll
        for (int j = 0; j < 8; ++j) {
            float s = 0.f;
            #pragma unroll
            for (int t = 0; t < 3; ++t) s += win[j + 28 + t] * W[t];
            yb[(long)(l0 + j) * 3072] = f2bf(s);
        }
    }
}

// ---------------------------------------------------------------------------
// bn features: bn[bl,12] = [mean|ms| | mean|dt| | mean|v|] per head.
// ---------------------------------------------------------------------------
__global__ __launch_bounds__(256) void build_bn(const float* __restrict__ ms,
    const float* __restrict__ dt, const float* __restrict__ v,
    float* __restrict__ bn)
{
    const int bl = blockIdx.x, tid = threadIdx.x;
    const long rb = (long)bl * 1024;
    const int wid = tid >> 6, lane = tid & 63;
    const long base = rb + wid * 256 + lane * 4;
    float* g = bn + (long)bl * 12;
    float4 a;
    float s;
    a = *(const float4*)(ms + base);
    s = fabsf(a.x) + fabsf(a.y) + fabsf(a.z) + fabsf(a.w);
    for (int off = 32; off > 0; off >>= 1) s += __shfl_down(s, off);
    if (lane == 0) g[wid] = s * (1.f / 256.f);
    a = *(const float4*)(dt + base);
    s = fabsf(a.x) + fabsf(a.y) + fabsf(a.z) + fabsf(a.w);
    for (int off = 32; off > 0; off >>= 1) s += __shfl_down(s, off);
    if (lane == 0) g[4 + wid] = s * (1.f / 256.f);
    a = *(const float4*)(v + base);
    s = fabsf(a.x) + fabsf(a.y) + fabsf(a.z) + fabsf(a.w);
    for (int off = 32; off > 0; off >>= 1) s += __shfl_down(s, off);
    if (lane == 0) g[8 + wid] = s * (1.f / 256.f);
}

// ---------------------------------------------------------------------------
// Blend + per-head RMSNorm * o_norm_w -> bf16 out.
// ---------------------------------------------------------------------------
__global__ __launch_bounds__(256) void blend_rms(const float* __restrict__ ms,
    const float* __restrict__ dt, const float* __restrict__ v,
    const float* __restrict__ wts, const float* __restrict__ onw,
    ushort* __restrict__ o)
{
    const int bl = blockIdx.x, tid = threadIdx.x;
    const int wid = tid >> 6, lane = tid & 63;
    const long base = (long)bl * 1024 + wid * 256 + lane * 4;
    const float* wr = wts + (long)bl * 12 + wid * 3;
    const float w0 = wr[0], w1 = wr[1], w2 = wr[2];
    const float4 m = *(const float4*)(ms + base);
    const float4 d = *(const float4*)(dt + base);
    const float4 x = *(const float4*)(v + base);
    float4 ov;
    ov.x = w0 * m.x + w1 * d.x + w2 * x.x;
    ov.y = w0 * m.y + w1 * d.y + w2 * x.y;
    ov.z = w0 * m.z + w1 * d.z + w2 * x.z;
    ov.w = w0 * m.w + w1 * d.w + w2 * x.w;
    float ss = ov.x * ov.x + ov.y * ov.y + ov.z * ov.z + ov.w * ov.w;
    for (int off = 32; off > 0; off >>= 1) ss += __shfl_down(ss, off);
    ss = __shfl(ss, 0);
    const float inv = rsqrtf(ss * (1.f / 256.f) + 1e-5f);
    const float4 nw = *(const float4*)(onw + lane * 4);
    ushort4 ob;
    ob.x = f2bf(ov.x * inv * nw.x); ob.y = f2bf(ov.y * inv * nw.y);
    ob.z = f2bf(ov.z * inv * nw.z); ob.w = f2bf(ov.w * inv * nw.w);
    *(ushort4*)(o + base) = ob;
}

// ---------------------------------------------------------------------------
extern "C" void kernel_launch(void* const* d_in, const int* in_sizes, int n_in,
                              void* d_out, int out_size, void* d_ws, size_t ws_size,
                              hipStream_t stream)
{
    (void)in_sizes; (void)n_in; (void)out_size; (void)ws_size;
    const float* hid   = (const float*)d_in[0];
    const float* Wq    = (const float*)d_in[1];
    const float* Wk    = (const float*)d_in[2];
    const float* Wv    = (const float*)d_in[3];
    const float* Wb    = (const float*)d_in[4];
    const float* cq    = (const float*)d_in[5];
    const float* ck    = (const float*)d_in[6];
    const float* cv    = (const float*)d_in[7];
    const float* w3    = (const float*)d_in[8];
    const float* w15   = (const float*)d_in[9];
    const float* w31   = (const float*)d_in[10];
    const float* kmix  = (const float*)d_in[11];
    const float* cmix  = (const float*)d_in[12];
    const float* fw1   = (const float*)d_in[13];
    const float* fb1   = (const float*)d_in[14];
    const float* fw2   = (const float*)d_in[15];
    const float* fb2   = (const float*)d_in[16];
    const float* onw   = (const float*)d_in[17];
    const float* Wo    = (const float*)d_in[18];
    float* out = (float*)d_out;

    // ---- workspace carve (peak ~195 MiB) ----
    const size_t MiB = 1024 * 1024;
    char* W = (char*)d_ws;
    float*  s0    = (float*)(W);              // qlin -> u(f32) -> yms[lo] -> hdn16
    char*   s1c   = W + 32 * MiB;             // qtmp -> w16|kT16 -> yms[hi] -> msout
    float*  s1    = (float*)s1c;
    float*  s2    = (float*)(W + 64 * MiB);   // vlin -> dt
    char*   s3    = W + 96 * MiB;             // q16|k16 -> mix16|ofin16
    float*  s4    = (float*)(W + 128 * MiB);  // v (long-lived)
    ushort* hid16 = (ushort*)(W + 160 * MiB);
    ushort* WqT   = (ushort*)(W + 176 * MiB);
    ushort* WkT   = WqT   + 1024 * 1024;
    ushort* WvT   = WkT   + 1024 * 1024;
    ushort* cmixT = WvT   + 1024 * 1024;
    ushort* WoT   = cmixT + 1024 * 1024;
    ushort* fw1T  = WoT   + 1024 * 1024;      // [2048][1024]
    ushort* kmixT = fw1T  + 2048 * 1024;      // [256][768]
    float*  beta  = (float*)(W + 191 * MiB);  // 128 KB
    ushort* al16  = (ushort*)(W + 191 * MiB + 128 * 1024);  // 2 MiB
    float*  bnf   = (float*)(W + 193 * MiB + 128 * 1024);   // 384 KB
    float*  wts   = bnf + 98304;                            // 384 KB

    ushort* q16    = (ushort*)s3;
    ushort* k16    = (ushort*)(s3 + 16 * MiB);
    ushort* mix16  = q16;
    ushort* ofin16 = k16;
    ushort* yms16  = (ushort*)s0;             // 48 MiB spans s0+s1
    ushort* hdn16  = (ushort*)s0;
    float*  qlin = s0; float* qtmp = s1;
    float*  u = s0;
    ushort* w16  = (ushort*)s1c;              // 16 MiB
    ushort* kT16 = (ushort*)(s1c + 16 * MiB); // 16 MiB
    float*  dt = s2; float* v = s4; float* msout = s1;

    const dim3 T256(256);
    // 0. casts / weight transposes
    cast_bf16<<<8192, T256, 0, stream>>>(hid, hid16);
    transpose_cast<<<dim3(32, 32), T256, 0, stream>>>(Wq, WqT, 1024, 1024);
    transpose_cast<<<dim3(32, 32), T256, 0, stream>>>(Wk, WkT, 1024, 1024);
    transpose_cast<<<dim3(32, 32), T256, 0, stream>>>(Wv, WvT, 1024, 1024);
    transpose_cast<<<dim3(32, 32), T256, 0, stream>>>(cmix, cmixT, 1024, 1024);
    transpose_cast<<<dim3(32, 32), T256, 0, stream>>>(Wo, WoT, 1024, 1024);
    transpose_cast<<<dim3(64, 32), T256, 0, stream>>>(fw1, fw1T, 1024, 2048);
    transpose_cast<<<dim3(8, 24), T256, 0, stream>>>(kmix, kmixT, 768, 256);
    // 1. q pipeline
    gemm_mfma<0><<<dim3(8, 64), T256, 0, stream>>>(hid16, WqT, nullptr, nullptr, nullptr, qlin, 8192, 1024, 1024);
    conv4_silu<<<32768, T256, 0, stream>>>(qlin, cq, qtmp);
    l2norm_bf16<<<8192, T256, 0, stream>>>(qtmp, q16);
    // 2. k pipeline
    gemm_mfma<0><<<dim3(8, 64), T256, 0, stream>>>(hid16, WkT, nullptr, nullptr, nullptr, qlin, 8192, 1024, 1024);
    conv4_silu<<<32768, T256, 0, stream>>>(qlin, ck, qtmp);
    l2norm_bf16<<<8192, T256, 0, stream>>>(qtmp, k16);
    // 3. v pipeline
    gemm_mfma<0><<<dim3(8, 64), T256, 0, stream>>>(hid16, WvT, nullptr, nullptr, nullptr, qlin, 8192, 1024, 1024);
    conv4_silu<<<32768, T256, 0, stream>>>(qlin, cv, v);
    // 4. beta
    gemm_smallN<4, 0><<<8192, T256, 0, stream>>>(hid, Wb, nullptr, beta, 1024);
    // 5. delta rule: prep + MFMA scan (staged, dbuf, 1 wave/block)
    chunk_prep<<<1024, T256, 0, stream>>>(q16, k16, v, beta, u, w16, kT16, al16);
    delta_scan_mfma<<<256, dim3(64), 0, stream>>>(q16, kT16, w16, u, al16, dt);
    // 6. multiscale conv branch
    ms_conv<<<4096, T256, 0, stream>>>(v, w3, w15, w31, yms16);
    gemm_mfma<1><<<dim3(2, 256), T256, 0, stream>>>(yms16, kmixT, nullptr, nullptr, nullptr, mix16, 32768, 256, 768);
    gemm_mfma<0><<<dim3(8, 64), T256, 0, stream>>>(mix16, cmixT, nullptr, nullptr, nullptr, msout, 8192, 1024, 1024);
    // 7. fusion gate
    build_bn<<<8192, T256, 0, stream>>>(msout, dt, v, bnf);
    gemm_mfma<3><<<dim3(16, 64), T256, 0, stream>>>(hid16, fw1T, fb1, bnf, fw1 + 1024L * 2048, hdn16, 8192, 2048, 1024);
    gemm_smallN<12, 1><<<8192, T256, 0, stream>>>(hdn16, fw2, fb2, wts, 2048);
    // 8. blend + output projection
    blend_rms<<<8192, T256, 0, stream>>>(msout, dt, v, wts, onw, ofin16);
    gemm_mfma<0><<<dim3(8, 64), T256, 0, stream>>>(ofin16, WoT, nullptr, nullptr, nullptr, out, 8192, 1024, 1024);
}

// Round 9
// 773.325 us; speedup vs baseline: 1.2108x; 1.0824x over previous
//
#include <hip/hip_runtime.h>
#include <math.h>

// Problem constants: B=4, L=2048, D=1024, H=4, dk=dv=256, CHUNK=32, NCHUNK=64
// bf16 MFMA for all large GEMMs AND the delta-rule scan (all-register operand
// staging, 512-VGPR single-wave blocks).

typedef __attribute__((ext_vector_type(8))) __bf16 bf16x8;
typedef __attribute__((ext_vector_type(4))) float f32x4;

__device__ inline ushort f2bf(float f) {
    union { float f; unsigned u; } x; x.f = f;
    unsigned u = x.u;
    u += 0x7fffu + ((u >> 16) & 1u);
    return (ushort)(u >> 16);
}
__device__ inline float bf2f(ushort h) {
    union { unsigned u; float f; } x; x.u = ((unsigned)h) << 16;
    return x.f;
}
__device__ inline float ldf(float v) { return v; }
__device__ inline float ldf(ushort v) { return bf2f(v); }

// ---------------------------------------------------------------------------
// bf16 MFMA GEMM: C[M,N] = A[M,K] @ BT[N,K]^T. 128x128 tile, BK=64 (split-half
// LDS layout [2][128][32]). 4 waves. EPI 0: f32 out. 1: bf16 out.
// 3: bias+rank12+gelu, bf16 out. Requires K % 64 == 0.
// ---------------------------------------------------------------------------
template<int EPI>
__global__ __launch_bounds__(256) void gemm_mfma(
    const ushort* __restrict__ A, const ushort* __restrict__ BT,
    const float* __restrict__ bias, const float* __restrict__ extA,
    const float* __restrict__ extB, void* __restrict__ Cout,
    int M, int N, int K)
{
    __shared__ ushort As[2][128 * 32];
    __shared__ ushort Bs[2][128 * 32];
    __shared__ float bns[(EPI >= 2) ? 128 * 13 : 1];
    __shared__ float exb[(EPI >= 2) ? 12 * 128 : 1];
    const int tid = threadIdx.x;
    const int row0 = blockIdx.y * 128, col0 = blockIdx.x * 128;
    const int lane = tid & 63, wave = tid >> 6;
    const int wr = (wave >> 1) * 64, wc = (wave & 1) * 64;

    if (EPI >= 2) {
        for (int e = tid; e < 128 * 12; e += 256)
            bns[(e / 12) * 13 + (e % 12)] = extA[(long)(row0 + e / 12) * 12 + e % 12];
        for (int e = tid; e < 12 * 128; e += 256)
            exb[e] = extB[(long)(e >> 7) * N + col0 + (e & 127)];
    }

    f32x4 acc[4][4];
    #pragma unroll
    for (int m = 0; m < 4; ++m)
        #pragma unroll
        for (int n = 0; n < 4; ++n) {
            acc[m][n][0] = 0.f; acc[m][n][1] = 0.f;
            acc[m][n][2] = 0.f; acc[m][n][3] = 0.f;
        }

    const int rA = lane & 15;
    const int ko = (lane >> 4) * 8;
    const int srow = tid >> 2;
    const int skk = (tid & 3) * 8;

    for (int k0 = 0; k0 < K; k0 += 64) {
        #pragma unroll
        for (int hf = 0; hf < 2; ++hf) {
            #pragma unroll
            for (int i = 0; i < 2; ++i) {
                const long ga = (long)(row0 + i * 64 + srow) * K + k0 + hf * 32 + skk;
                __builtin_amdgcn_global_load_lds(
                    (const __attribute__((address_space(1))) void*)(A + ga),
                    (__attribute__((address_space(3))) void*)(&As[hf][0] + i * 2048 + wave * 512),
                    16, 0, 0);
                const long gb = (long)(col0 + i * 64 + srow) * K + k0 + hf * 32 + skk;
                __builtin_amdgcn_global_load_lds(
                    (const __attribute__((address_space(1))) void*)(BT + gb),
                    (__attribute__((address_space(3))) void*)(&Bs[hf][0] + i * 2048 + wave * 512),
                    16, 0, 0);
            }
        }
        __syncthreads();
        #pragma unroll
        for (int hf = 0; hf < 2; ++hf) {
            bf16x8 af[4], bfr[4];
            #pragma unroll
            for (int m = 0; m < 4; ++m)
                af[m] = *(const bf16x8*)(&As[hf][0] + (wr + m * 16 + rA) * 32 + ko);
            #pragma unroll
            for (int n = 0; n < 4; ++n)
                bfr[n] = *(const bf16x8*)(&Bs[hf][0] + (wc + n * 16 + rA) * 32 + ko);
            #pragma unroll
            for (int m = 0; m < 4; ++m)
                #pragma unroll
                for (int n = 0; n < 4; ++n)
                    acc[m][n] = __builtin_amdgcn_mfma_f32_16x16x32_bf16(af[m], bfr[n], acc[m][n], 0, 0, 0);
        }
        __syncthreads();
    }

    const int crow = (lane >> 4) * 4;
    const int ccol = lane & 15;
    #pragma unroll
    for (int m = 0; m < 4; ++m) {
        #pragma unroll
        for (int n = 0; n < 4; ++n) {
            #pragma unroll
            for (int r = 0; r < 4; ++r) {
                const int rl = wr + m * 16 + crow + r;
                const int cl = wc + n * 16 + ccol;
                float vv = acc[m][n][r];
                if (EPI >= 2) {
                    vv += bias[col0 + cl];
                    #pragma unroll
                    for (int j = 0; j < 12; ++j) vv += bns[rl * 13 + j] * exb[j * 128 + cl];
                    vv = 0.5f * vv * (1.f + erff(vv * 0.70710678118654752f));
                }
                const long off = (long)(row0 + rl) * N + col0 + cl;
                if (EPI == 0) ((float*)Cout)[off] = vv;
                else ((ushort*)Cout)[off] = f2bf(vv);
            }
        }
    }
}

// ---------------------------------------------------------------------------
// Transpose + cast to bf16: W[K][N] f32 -> WT[N][K] bf16.
// ---------------------------------------------------------------------------
__global__ __launch_bounds__(256) void transpose_cast(const float* __restrict__ W,
    ushort* __restrict__ WT, int K, int N)
{
    __shared__ float t[32][33];
    const int k0 = blockIdx.y * 32, n0 = blockIdx.x * 32;
    const int c = threadIdx.x & 31, r8 = threadIdx.x >> 5;
    #pragma unroll
    for (int rr = 0; rr < 4; ++rr) {
        const int r = r8 + rr * 8;
        t[r][c] = W[(long)(k0 + r) * N + n0 + c];
    }
    __syncthreads();
    #pragma unroll
    for (int rr = 0; rr < 4; ++rr) {
        const int r = r8 + rr * 8;
        WT[(long)(n0 + r) * K + k0 + c] = f2bf(t[c][r]);
    }
}

__global__ __launch_bounds__(256) void cast_bf16(const float* __restrict__ x,
    ushort* __restrict__ y)
{
    const long i = ((long)blockIdx.x * 256 + threadIdx.x) * 4;
    const float4 v = *(const float4*)(x + i);
    ushort4 o;
    o.x = f2bf(v.x); o.y = f2bf(v.y); o.z = f2bf(v.z); o.w = f2bf(v.w);
    *(ushort4*)(y + i) = o;
}

// ---------------------------------------------------------------------------
// Small-N GEMM. MODE 0: sigmoid. MODE 1: +bias, per-head softmax over triples.
// ---------------------------------------------------------------------------
template<int NOUT, int MODE, typename TA>
__global__ __launch_bounds__(256) void gemm_smallN(const TA* __restrict__ A,
    const float* __restrict__ Bm, const float* __restrict__ bias,
    float* __restrict__ Cm, int K)
{
    __shared__ float part[4][NOUT];
    __shared__ float sm[NOUT];
    const int m = blockIdx.x, tid = threadIdx.x;
    const TA* ar = A + (long)m * K;
    float acc[NOUT];
    #pragma unroll
    for (int j = 0; j < NOUT; ++j) acc[j] = 0.f;
    for (int k = tid; k < K; k += 256) {
        const float a = ldf(ar[k]);
        #pragma unroll
        for (int j = 0; j < NOUT; ++j) acc[j] += a * Bm[(long)k * NOUT + j];
    }
    #pragma unroll
    for (int j = 0; j < NOUT; ++j)
        for (int off = 32; off > 0; off >>= 1) acc[j] += __shfl_down(acc[j], off);
    const int wid = tid >> 6, lane = tid & 63;
    if (lane == 0) {
        #pragma unroll
        for (int j = 0; j < NOUT; ++j) part[wid][j] = acc[j];
    }
    __syncthreads();
    if (tid < NOUT) {
        float s = part[0][tid] + part[1][tid] + part[2][tid] + part[3][tid];
        if (MODE == 0) {
            Cm[(long)m * NOUT + tid] = 1.f / (1.f + expf(-s));
        } else {
            sm[tid] = s + bias[tid];
        }
    }
    if (MODE == 1) {
        __syncthreads();
        if (tid < NOUT) {
            const int hh = tid / 3, r = tid - hh * 3;
            const float a0 = sm[hh * 3], a1 = sm[hh * 3 + 1], a2 = sm[hh * 3 + 2];
            const float mx = fmaxf(a0, fmaxf(a1, a2));
            const float e0 = expf(a0 - mx), e1 = expf(a1 - mx), e2 = expf(a2 - mx);
            const float mine = (r == 0) ? e0 : ((r == 1) ? e1 : e2);
            Cm[(long)m * NOUT + tid] = mine / (e0 + e1 + e2);
        }
    }
}

// ---------------------------------------------------------------------------
// Depthwise causal conv (k=4) + SiLU, fp32 -> fp32.
// ---------------------------------------------------------------------------
__global__ __launch_bounds__(256) void conv4_silu(const float* __restrict__ x,
    const float* __restrict__ wc, float* __restrict__ y)
{
    const long idx = (long)blockIdx.x * 256 + threadIdx.x;
    const int c = (int)(idx & 1023);
    const long bl = idx >> 10;
    const int l = (int)(bl & 2047);
    const long b = bl >> 11;
    const float* xp = x + b * 2048 * 1024 + c;
    const float* wp = wc + c * 4;
    float s = 0.f;
    #pragma unroll
    for (int t = 0; t < 4; ++t) {
        const int ll = l - 3 + t;
        if (ll >= 0) s += xp[(long)ll * 1024] * wp[t];
    }
    y[idx] = s / (1.f + expf(-s));
}

// ---------------------------------------------------------------------------
// l2 normalize rows of 256 (fp32 in), write bf16.
// ---------------------------------------------------------------------------
__global__ __launch_bounds__(256) void l2norm_bf16(const float* __restrict__ x,
    ushort* __restrict__ y)
{
    const long wid = ((long)blockIdx.x * 256 + threadIdx.x) >> 6;
    const int lane = threadIdx.x & 63;
    const float4 xv = *(const float4*)(x + wid * 256 + lane * 4);
    float ss = xv.x * xv.x + xv.y * xv.y + xv.z * xv.z + xv.w * xv.w;
    for (int off = 32; off > 0; off >>= 1) ss += __shfl_down(ss, off);
    ss = __shfl(ss, 0);
    const float inv = rsqrtf(ss + 1e-6f);
    ushort4 o;
    o.x = f2bf(xv.x * inv); o.y = f2bf(xv.y * inv);
    o.z = f2bf(xv.z * inv); o.w = f2bf(xv.w * inv);
    *(ushort4*)(y + wid * 256 + lane * 4) = o;
}

// ---------------------------------------------------------------------------
// Chunk prep. Outputs: u (f32), w16 [blk][32][256] bf16, kT16 [blk][256][32]
// bf16, al16 [blk][32][32] bf16.
// ---------------------------------------------------------------------------
__global__ __launch_bounds__(256) void chunk_prep(
    const ushort* __restrict__ qn, const ushort* __restrict__ kn,
    const float* __restrict__ v, const float* __restrict__ beta,
    float* __restrict__ u, ushort* __restrict__ w16,
    ushort* __restrict__ kT16, ushort* __restrict__ al16)
{
    __shared__ float kb_s[32 * 256];
    __shared__ float bufB[32 * 256];
    __shared__ float Ms[32 * 33];
    __shared__ float Rs[32 * 33];
    __shared__ float bet[32];
    const int blk = blockIdx.x;
    const int n = blk & 63;
    const int bh = blk >> 6;
    const int h = bh & 3;
    const int b = bh >> 2;
    const int tid = threadIdx.x;
    const long lbase = (long)b * 2048 + n * 32;

    if (tid < 32) bet[tid] = beta[(lbase + tid) * 4 + h];
    __syncthreads();
    for (int e = tid; e < 8192; e += 256) {
        const int c = e >> 8, dd = e & 255;
        const float kv = bf2f(kn[(lbase + c) * 1024 + h * 256 + dd]);
        bufB[dd * 32 + c] = kv;
        kb_s[c * 256 + dd] = kv * bet[c];
    }
    __syncthreads();
    for (int e = tid; e < 8192; e += 256)
        kT16[(long)blk * 8192 + e] = f2bf(bufB[e]);

    const int j = tid & 31, i0 = tid >> 5;
    {
        float m4[4] = {0.f, 0.f, 0.f, 0.f};
        for (int dd = 0; dd < 256; ++dd) {
            const float kt = bufB[dd * 32 + j];
            #pragma unroll
            for (int ii = 0; ii < 4; ++ii) m4[ii] += kb_s[(i0 + 8 * ii) * 256 + dd] * kt;
        }
        #pragma unroll
        for (int ii = 0; ii < 4; ++ii) {
            const int i = i0 + 8 * ii;
            const float mv = (i > j) ? -m4[ii] : 0.f;
            Ms[i * 33 + j] = mv;
            Rs[i * 33 + j] = mv + ((i == j) ? 1.f : 0.f);
        }
    }
    {
        float a4[4] = {0.f, 0.f, 0.f, 0.f};
        for (int dd = 0; dd < 256; ++dd) {
            const float kt = bufB[dd * 32 + j];
            #pragma unroll
            for (int ii = 0; ii < 4; ++ii)
                a4[ii] += bf2f(qn[(lbase + (i0 + 8 * ii)) * 1024 + h * 256 + dd]) * kt;
        }
        #pragma unroll
        for (int ii = 0; ii < 4; ++ii) {
            const int i = i0 + 8 * ii;
            al16[(long)blk * 1024 + i * 32 + j] = f2bf((i >= j) ? a4[ii] : 0.f);
        }
    }
    __syncthreads();
    for (int it = 0; it < 4; ++it) {
        float p4[4] = {0.f, 0.f, 0.f, 0.f};
        for (int kk = 0; kk < 32; ++kk) {
            const float pb = Ms[kk * 33 + j];
            #pragma unroll
            for (int ii = 0; ii < 4; ++ii) p4[ii] += Ms[(i0 + 8 * ii) * 33 + kk] * pb;
        }
        __syncthreads();
        #pragma unroll
        for (int ii = 0; ii < 4; ++ii) Ms[(i0 + 8 * ii) * 33 + j] = p4[ii];
        __syncthreads();
        float r4[4] = {0.f, 0.f, 0.f, 0.f};
        for (int kk = 0; kk < 32; ++kk) {
            const float pb = Ms[kk * 33 + j];
            #pragma unroll
            for (int ii = 0; ii < 4; ++ii) r4[ii] += Rs[(i0 + 8 * ii) * 33 + kk] * pb;
        }
        __syncthreads();
        #pragma unroll
        for (int ii = 0; ii < 4; ++ii) Rs[(i0 + 8 * ii) * 33 + j] += r4[ii];
        __syncthreads();
    }
    for (int e = tid; e < 8192; e += 256) {
        const int c = e >> 8, dd = e & 255;
        bufB[c * 256 + dd] = v[(lbase + c) * 1024 + h * 256 + dd] * bet[c];
    }
    __syncthreads();
    {
        const int dd = tid;
        float accU[32], accW[32];
        #pragma unroll
        for (int r = 0; r < 32; ++r) { accU[r] = 0.f; accW[r] = 0.f; }
        for (int kk = 0; kk < 32; ++kk) {
            const float vv = bufB[kk * 256 + dd];
            const float bb = kb_s[kk * 256 + dd];
            #pragma unroll
            for (int r = 0; r < 32; ++r) {
                const float rr = Rs[r * 33 + kk];
                accU[r] += rr * vv;
                accW[r] += rr * bb;
            }
        }
        const long base = (long)blk * 32;
        #pragma unroll
        for (int r = 0; r < 32; ++r) {
            u  [(base + r) * 256 + dd] = accU[r];
            w16[(base + r) * 256 + dd] = f2bf(accW[r]);
        }
    }
}

// ---------------------------------------------------------------------------
// MFMA delta scan, 256 x 1-wave blocks, ALL-REGISTER operand staging.
// __launch_bounds__(64,1) unlocks 512 VGPR/wave (occupancy is 1 wave/SIMD
// regardless). All operand frags (w 16, q 16, kT 16, al 2) live in registers,
// prefetched one phase ahead of use via plain global loads (compiler tracks
// per-register deps; no manual vmcnt, no LDS aliasing hazards). Sb/Ub LDS
// roundtrips (C-layout -> B-frag swap) kept — distinct static arrays.
// Per chunk (math identical to the verified round-4 scan):
//   u' = u - w@S ; o = q@S + aloc@u' ; S += kT@u'
// ---------------------------------------------------------------------------
__global__ __launch_bounds__(64, 1) void delta_scan_mfma(
    const ushort* __restrict__ q16, const ushort* __restrict__ kT16,
    const ushort* __restrict__ w16, const float* __restrict__ u,
    const ushort* __restrict__ al16, float* __restrict__ dt)
{
    __shared__ __align__(16) ushort Sb[16 * 264];
    __shared__ __align__(16) ushort Ub[16 * 40];
    const int blk = blockIdx.x;
    const int bh = blk & 15;
    const int sl = blk >> 4;
    const int h = bh & 3;
    const int b = bh >> 2;
    const int v0 = sl * 16;
    const int lane = threadIdx.x;
    const int col = lane & 15;
    const int grp = lane >> 4;

    // per-lane base pointers (verified round-4 indexing)
    const ushort* wp  = w16  + ((long)bh * 64 * 32 + col) * 256 + grp * 8;
    const ushort* qp  = q16  + ((long)b * 2048 + col) * 1024 + h * 256 + grp * 8;
    const ushort* kp  = kT16 + ((long)bh * 64 * 256 + col) * 32 + grp * 8;
    const ushort* ap  = al16 + ((long)bh * 64 * 32 + col) * 32 + grp * 8;
    const float*  Ug  = u    + ((long)bh * 64 * 32 + grp * 4) * 256 + v0 + col;
    float*        dp  = dt   + ((long)b * 2048 + grp * 4) * 1024 + h * 256 + v0 + col;

    f32x4 S[16];
    #pragma unroll
    for (int t = 0; t < 16; ++t) { S[t][0] = 0.f; S[t][1] = 0.f; S[t][2] = 0.f; S[t][3] = 0.f; }

    bf16x8 wf[2][8], qf[2][8], kf[16], alf[2], sf[8];
    float upre[8];

    // sf = 0 for chunk 0 (S = 0)
    #pragma unroll
    for (int kb = 0; kb < 8; ++kb)
        #pragma unroll
        for (int e = 0; e < 8; ++e) sf[kb][e] = (__bf16)0.f;

    // prologue: load chunk-0 operands into registers
    #pragma unroll
    for (int rt = 0; rt < 2; ++rt)
        #pragma unroll
        for (int kb = 0; kb < 8; ++kb) {
            wf[rt][kb] = *(const bf16x8*)(wp + rt * 4096 + kb * 32);
            qf[rt][kb] = *(const bf16x8*)(qp + (long)rt * 16384 + kb * 32);
        }
    #pragma unroll
    for (int t = 0; t < 16; ++t) kf[t] = *(const bf16x8*)(kp + t * 512);
    alf[0] = *(const bf16x8*)(ap);
    alf[1] = *(const bf16x8*)(ap + 512);
    #pragma unroll
    for (int rt = 0; rt < 2; ++rt)
        #pragma unroll
        for (int r = 0; r < 4; ++r)
            upre[rt * 4 + r] = Ug[rt * 4096 + r * 256];

    for (int n = 0; n < 64; ++n) {
        // --- u' = u - w@S  (consumes wf, sf, upre)
        f32x4 up[2];
        #pragma unroll
        for (int rt = 0; rt < 2; ++rt) {
            f32x4 a; a[0] = 0.f; a[1] = 0.f; a[2] = 0.f; a[3] = 0.f;
            #pragma unroll
            for (int kb = 0; kb < 8; ++kb)
                a = __builtin_amdgcn_mfma_f32_16x16x32_bf16(wf[rt][kb], sf[kb], a, 0, 0, 0);
            #pragma unroll
            for (int r = 0; r < 4; ++r)
                up[rt][r] = upre[rt * 4 + r] - a[r];
        }
        // prefetch w(n+1) (wf dead)
        if (n < 63) {
            #pragma unroll
            for (int rt = 0; rt < 2; ++rt)
                #pragma unroll
                for (int kb = 0; kb < 8; ++kb)
                    wf[rt][kb] = *(const bf16x8*)(wp + (long)(n + 1) * 8192 + rt * 4096 + kb * 32);
        }

        // --- u' C-layout -> B-frag via Ub
        #pragma unroll
        for (int rt = 0; rt < 2; ++rt) {
            ushort4 p;
            p.x = f2bf(up[rt][0]); p.y = f2bf(up[rt][1]);
            p.z = f2bf(up[rt][2]); p.w = f2bf(up[rt][3]);
            *(ushort4*)&Ub[col * 40 + rt * 16 + grp * 4] = p;
        }
        const bf16x8 uf = *(const bf16x8*)&Ub[col * 40 + grp * 8];

        // --- o = q@S + aloc@u' ; store to dt  (consumes qf, alf)
        #pragma unroll
        for (int rt = 0; rt < 2; ++rt) {
            f32x4 a; a[0] = 0.f; a[1] = 0.f; a[2] = 0.f; a[3] = 0.f;
            #pragma unroll
            for (int kb = 0; kb < 8; ++kb)
                a = __builtin_amdgcn_mfma_f32_16x16x32_bf16(qf[rt][kb], sf[kb], a, 0, 0, 0);
            a = __builtin_amdgcn_mfma_f32_16x16x32_bf16(alf[rt], uf, a, 0, 0, 0);
            #pragma unroll
            for (int r = 0; r < 4; ++r)
                dp[(long)n * 32768 + rt * 16384 + r * 1024] = a[r];
        }
        // prefetch q(n+1), al(n+1) (qf, alf dead)
        if (n < 63) {
            #pragma unroll
            for (int rt = 0; rt < 2; ++rt)
                #pragma unroll
                for (int kb = 0; kb < 8; ++kb)
                    qf[rt][kb] = *(const bf16x8*)(qp + (long)(n + 1) * 32768 + (long)rt * 16384 + kb * 32);
            alf[0] = *(const bf16x8*)(ap + (long)(n + 1) * 1024);
            alf[1] = *(const bf16x8*)(ap + (long)(n + 1) * 1024 + 512);
        }

        // --- S += kT @ u'  (consumes kf)
        #pragma unroll
        for (int t = 0; t < 16; ++t)
            S[t] = __builtin_amdgcn_mfma_f32_16x16x32_bf16(kf[t], uf, S[t], 0, 0, 0);
        // prefetch kT(n+1), u(n+1) (kf, upre dead)
        if (n < 63) {
            #pragma unroll
            for (int t = 0; t < 16; ++t)
                kf[t] = *(const bf16x8*)(kp + (long)(n + 1) * 8192 + t * 512);
            #pragma unroll
            for (int rt = 0; rt < 2; ++rt)
                #pragma unroll
                for (int r = 0; r < 4; ++r)
                    upre[rt * 4 + r] = Ug[(long)(n + 1) * 8192 + rt * 4096 + r * 256];
        }

        // --- S C-layout -> B-frag via Sb (sf for next chunk)
        #pragma unroll
        for (int t = 0; t < 16; ++t) {
            ushort4 p;
            p.x = f2bf(S[t][0]); p.y = f2bf(S[t][1]);
            p.z = f2bf(S[t][2]); p.w = f2bf(S[t][3]);
            *(ushort4*)&Sb[col * 264 + t * 16 + grp * 4] = p;
        }
        #pragma unroll
        for (int kb = 0; kb < 8; ++kb)
            sf[kb] = *(const bf16x8*)&Sb[col * 264 + kb * 32 + grp * 8];
    }
}

// ---------------------------------------------------------------------------
// Multiscale causal depthwise conv -> bf16 out. Flat-index identity:
// y[(b*2048+l)*3072 + sc*1024 + c]. Thread = (b, c, 8-l window).
// ---------------------------------------------------------------------------
__global__ __launch_bounds__(256) void ms_conv(const float* __restrict__ v,
    const float* __restrict__ w3, const float* __restrict__ w15,
    const float* __restrict__ w31, ushort* __restrict__ y)
{
    const int bid = blockIdx.x;
    const int b = bid >> 10;
    const int oct = (bid >> 2) & 255;
    const int c = ((bid & 3) << 8) + threadIdx.x;
    const int l0 = oct << 3;
    const float* vb = v + ((long)b * 2048) * 1024 + c;
    ushort* yb = y + ((long)b * 2048) * 3072 + c;

    float win[38];
    #pragma unroll
    for (int t = 0; t < 38; ++t) {
        const int ll = l0 - 30 + t;
        win[t] = (ll >= 0) ? vb[(long)ll * 1024] : 0.f;
    }
    {
        float W[31];
        #pragma unroll
        for (int t = 0; t < 31; ++t) W[t] = w31[c * 31 + t];
        #pragma unroll
        for (int j = 0; j < 8; ++j) {
            float s = 0.f;
            #pragma unroll
            for (int t = 0; t < 31; ++t) s += win[j + t] * W[t];
            yb[(long)(l0 + j) * 3072 + 2048] = f2bf(s);
        }
    }
    {
        float W[15];
        #pragma unroll
        for (int t = 0; t < 15; ++t) W[t] = w15[c * 15 + t];
        #pragma unroll
        for (int j = 0; j < 8; ++j) {
            float s = 0.f;
            #pragma unroll
            for (int t = 0; t < 15; ++t) s += win[j + 16 + t] * W[t];
            yb[(long)(l0 + j) * 3072 + 1024] = f2bf(s);
        }
    }
    {
        float W[3];
        #pragma unroll
        for (int t = 0; t < 3; ++t) W[t] = w3[c * 3 + t];
        #pragma unroll
        for (int j = 0; j < 8; ++j) {
            float s = 0.f;
            #pragma unroll
            for (int t = 0; t < 3; ++t) s += win[j + 28 + t] * W[t];
            yb[(long)(l0 + j) * 3072] = f2bf(s);
        }
    }
}

// ---------------------------------------------------------------------------
// bn features: bn[bl,12] = [mean|ms| | mean|dt| | mean|v|] per head.
// ---------------------------------------------------------------------------
__global__ __launch_bounds__(256) void build_bn(const float* __restrict__ ms,
    const float* __restrict__ dt, const float* __restrict__ v,
    float* __restrict__ bn)
{
    const int bl = blockIdx.x, tid = threadIdx.x;
    const long rb = (long)bl * 1024;
    const int wid = tid >> 6, lane = tid & 63;
    const long base = rb + wid * 256 + lane * 4;
    float* g = bn + (long)bl * 12;
    float4 a;
    float s;
    a = *(const float4*)(ms + base);
    s = fabsf(a.x) + fabsf(a.y) + fabsf(a.z) + fabsf(a.w);
    for (int off = 32; off > 0; off >>= 1) s += __shfl_down(s, off);
    if (lane == 0) g[wid] = s * (1.f / 256.f);
    a = *(const float4*)(dt + base);
    s = fabsf(a.x) + fabsf(a.y) + fabsf(a.z) + fabsf(a.w);
    for (int off = 32; off > 0; off >>= 1) s += __shfl_down(s, off);
    if (lane == 0) g[4 + wid] = s * (1.f / 256.f);
    a = *(const float4*)(v + base);
    s = fabsf(a.x) + fabsf(a.y) + fabsf(a.z) + fabsf(a.w);
    for (int off = 32; off > 0; off >>= 1) s += __shfl_down(s, off);
    if (lane == 0) g[8 + wid] = s * (1.f / 256.f);
}

// ---------------------------------------------------------------------------
// Blend + per-head RMSNorm * o_norm_w -> bf16 out.
// ---------------------------------------------------------------------------
__global__ __launch_bounds__(256) void blend_rms(const float* __restrict__ ms,
    const float* __restrict__ dt, const float* __restrict__ v,
    const float* __restrict__ wts, const float* __restrict__ onw,
    ushort* __restrict__ o)
{
    const int bl = blockIdx.x, tid = threadIdx.x;
    const int wid = tid >> 6, lane = tid & 63;
    const long base = (long)bl * 1024 + wid * 256 + lane * 4;
    const float* wr = wts + (long)bl * 12 + wid * 3;
    const float w0 = wr[0], w1 = wr[1], w2 = wr[2];
    const float4 m = *(const float4*)(ms + base);
    const float4 d = *(const float4*)(dt + base);
    const float4 x = *(const float4*)(v + base);
    float4 ov;
    ov.x = w0 * m.x + w1 * d.x + w2 * x.x;
    ov.y = w0 * m.y + w1 * d.y + w2 * x.y;
    ov.z = w0 * m.z + w1 * d.z + w2 * x.z;
    ov.w = w0 * m.w + w1 * d.w + w2 * x.w;
    float ss = ov.x * ov.x + ov.y * ov.y + ov.z * ov.z + ov.w * ov.w;
    for (int off = 32; off > 0; off >>= 1) ss += __shfl_down(ss, off);
    ss = __shfl(ss, 0);
    const float inv = rsqrtf(ss * (1.f / 256.f) + 1e-5f);
    const float4 nw = *(const float4*)(onw + lane * 4);
    ushort4 ob;
    ob.x = f2bf(ov.x * inv * nw.x); ob.y = f2bf(ov.y * inv * nw.y);
    ob.z = f2bf(ov.z * inv * nw.z); ob.w = f2bf(ov.w * inv * nw.w);
    *(ushort4*)(o + base) = ob;
}

// ---------------------------------------------------------------------------
extern "C" void kernel_launch(void* const* d_in, const int* in_sizes, int n_in,
                              void* d_out, int out_size, void* d_ws, size_t ws_size,
                              hipStream_t stream)
{
    (void)in_sizes; (void)n_in; (void)out_size; (void)ws_size;
    const float* hid   = (const float*)d_in[0];
    const float* Wq    = (const float*)d_in[1];
    const float* Wk    = (const float*)d_in[2];
    const float* Wv    = (const float*)d_in[3];
    const float* Wb    = (const float*)d_in[4];
    const float* cq    = (const float*)d_in[5];
    const float* ck    = (const float*)d_in[6];
    const float* cv    = (const float*)d_in[7];
    const float* w3    = (const float*)d_in[8];
    const float* w15   = (const float*)d_in[9];
    const float* w31   = (const float*)d_in[10];
    const float* kmix  = (const float*)d_in[11];
    const float* cmix  = (const float*)d_in[12];
    const float* fw1   = (const float*)d_in[13];
    const float* fb1   = (const float*)d_in[14];
    const float* fw2   = (const float*)d_in[15];
    const float* fb2   = (const float*)d_in[16];
    const float* onw   = (const float*)d_in[17];
    const float* Wo    = (const float*)d_in[18];
    float* out = (float*)d_out;

    // ---- workspace carve (peak ~195 MiB) ----
    const size_t MiB = 1024 * 1024;
    char* W = (char*)d_ws;
    float*  s0    = (float*)(W);              // qlin -> u(f32) -> yms[lo] -> hdn16
    char*   s1c   = W + 32 * MiB;             // qtmp -> w16|kT16 -> yms[hi] -> msout
    float*  s1    = (float*)s1c;
    float*  s2    = (float*)(W + 64 * MiB);   // vlin -> dt
    char*   s3    = W + 96 * MiB;             // q16|k16 -> mix16|ofin16
    float*  s4    = (float*)(W + 128 * MiB);  // v (long-lived)
    ushort* hid16 = (ushort*)(W + 160 * MiB);
    ushort* WqT   = (ushort*)(W + 176 * MiB);
    ushort* WkT   = WqT   + 1024 * 1024;
    ushort* WvT   = WkT   + 1024 * 1024;
    ushort* cmixT = WvT   + 1024 * 1024;
    ushort* WoT   = cmixT + 1024 * 1024;
    ushort* fw1T  = WoT   + 1024 * 1024;      // [2048][1024]
    ushort* kmixT = fw1T  + 2048 * 1024;      // [256][768]
    float*  beta  = (float*)(W + 191 * MiB);  // 128 KB
    ushort* al16  = (ushort*)(W + 191 * MiB + 128 * 1024);  // 2 MiB
    float*  bnf   = (float*)(W + 193 * MiB + 128 * 1024);   // 384 KB
    float*  wts   = bnf + 98304;                            // 384 KB

    ushort* q16    = (ushort*)s3;
    ushort* k16    = (ushort*)(s3 + 16 * MiB);
    ushort* mix16  = q16;
    ushort* ofin16 = k16;
    ushort* yms16  = (ushort*)s0;             // 48 MiB spans s0+s1
    ushort* hdn16  = (ushort*)s0;
    float*  qlin = s0; float* qtmp = s1;
    float*  u = s0;
    ushort* w16  = (ushort*)s1c;              // 16 MiB
    ushort* kT16 = (ushort*)(s1c + 16 * MiB); // 16 MiB
    float*  dt = s2; float* v = s4; float* msout = s1;

    const dim3 T256(256);
    // 0. casts / weight transposes
    cast_bf16<<<8192, T256, 0, stream>>>(hid, hid16);
    transpose_cast<<<dim3(32, 32), T256, 0, stream>>>(Wq, WqT, 1024, 1024);
    transpose_cast<<<dim3(32, 32), T256, 0, stream>>>(Wk, WkT, 1024, 1024);
    transpose_cast<<<dim3(32, 32), T256, 0, stream>>>(Wv, WvT, 1024, 1024);
    transpose_cast<<<dim3(32, 32), T256, 0, stream>>>(cmix, cmixT, 1024, 1024);
    transpose_cast<<<dim3(32, 32), T256, 0, stream>>>(Wo, WoT, 1024, 1024);
    transpose_cast<<<dim3(64, 32), T256, 0, stream>>>(fw1, fw1T, 1024, 2048);
    transpose_cast<<<dim3(8, 24), T256, 0, stream>>>(kmix, kmixT, 768, 256);
    // 1. q pipeline
    gemm_mfma<0><<<dim3(8, 64), T256, 0, stream>>>(hid16, WqT, nullptr, nullptr, nullptr, qlin, 8192, 1024, 1024);
    conv4_silu<<<32768, T256, 0, stream>>>(qlin, cq, qtmp);
    l2norm_bf16<<<8192, T256, 0, stream>>>(qtmp, q16);
    // 2. k pipeline
    gemm_mfma<0><<<dim3(8, 64), T256, 0, stream>>>(hid16, WkT, nullptr, nullptr, nullptr, qlin, 8192, 1024, 1024);
    conv4_silu<<<32768, T256, 0, stream>>>(qlin, ck, qtmp);
    l2norm_bf16<<<8192, T256, 0, stream>>>(qtmp, k16);
    // 3. v pipeline
    gemm_mfma<0><<<dim3(8, 64), T256, 0, stream>>>(hid16, WvT, nullptr, nullptr, nullptr, qlin, 8192, 1024, 1024);
    conv4_silu<<<32768, T256, 0, stream>>>(qlin, cv, v);
    // 4. beta
    gemm_smallN<4, 0><<<8192, T256, 0, stream>>>(hid, Wb, nullptr, beta, 1024);
    // 5. delta rule: prep + MFMA scan (all-register staging, 1 wave/block)
    chunk_prep<<<1024, T256, 0, stream>>>(q16, k16, v, beta, u, w16, kT16, al16);
    delta_scan_mfma<<<256, dim3(64), 0, stream>>>(q16, kT16, w16, u, al16, dt);
    // 6. multiscale conv branch
    ms_conv<<<4096, T256, 0, stream>>>(v, w3, w15, w31, yms16);
    gemm_mfma<1><<<dim3(2, 256), T256, 0, stream>>>(yms16, kmixT, nullptr, nullptr, nullptr, mix16, 32768, 256, 768);
    gemm_mfma<0><<<dim3(8, 64), T256, 0, stream>>>(mix16, cmixT, nullptr, nullptr, nullptr, msout, 8192, 1024, 1024);
    // 7. fusion gate
    build_bn<<<8192, T256, 0, stream>>>(msout, dt, v, bnf);
    gemm_mfma<3><<<dim3(16, 64), T256, 0, stream>>>(hid16, fw1T, fb1, bnf, fw1 + 1024L * 2048, hdn16, 8192, 2048, 1024);
    gemm_smallN<12, 1><<<8192, T256, 0, stream>>>(hdn16, fw2, fb2, wts, 2048);
    // 8. blend + output projection
    blend_rms<<<8192, T256, 0, stream>>>(msout, dt, v, wts, onw, ofin16);
    gemm_mfma<0><<<dim3(8, 64), T256, 0, stream>>>(ofin16, WoT, nullptr, nullptr, nullptr, out, 8192, 1024, 1024);
}

// Round 10
// 722.006 us; speedup vs baseline: 1.2969x; 1.0711x over previous
//
#include <hip/hip_runtime.h>
#include <math.h>

// Problem constants: B=4, L=2048, D=1024, H=4, dk=dv=256, CHUNK=32, NCHUNK=64
// bf16 MFMA for all large GEMMs, the delta-rule scan (all-register staging),
// and chunk_prep's M/aloc GEMM phases.

typedef __attribute__((ext_vector_type(8))) __bf16 bf16x8;
typedef __attribute__((ext_vector_type(4))) float f32x4;

__device__ inline ushort f2bf(float f) {
    union { float f; unsigned u; } x; x.f = f;
    unsigned u = x.u;
    u += 0x7fffu + ((u >> 16) & 1u);
    return (ushort)(u >> 16);
}
__device__ inline float bf2f(ushort h) {
    union { unsigned u; float f; } x; x.u = ((unsigned)h) << 16;
    return x.f;
}
__device__ inline float ldf(float v) { return v; }
__device__ inline float ldf(ushort v) { return bf2f(v); }

// ---------------------------------------------------------------------------
// bf16 MFMA GEMM: C[M,N] = A[M,K] @ BT[N,K]^T. 128x128 tile, BK=64 (split-half
// LDS layout [2][128][32]). 4 waves. EPI 0: f32 out. 1: bf16 out.
// 3: bias+rank12+gelu, bf16 out. Requires K % 64 == 0.
// ---------------------------------------------------------------------------
template<int EPI>
__global__ __launch_bounds__(256) void gemm_mfma(
    const ushort* __restrict__ A, const ushort* __restrict__ BT,
    const float* __restrict__ bias, const float* __restrict__ extA,
    const float* __restrict__ extB, void* __restrict__ Cout,
    int M, int N, int K)
{
    __shared__ ushort As[2][128 * 32];
    __shared__ ushort Bs[2][128 * 32];
    __shared__ float bns[(EPI >= 2) ? 128 * 13 : 1];
    __shared__ float exb[(EPI >= 2) ? 12 * 128 : 1];
    const int tid = threadIdx.x;
    const int row0 = blockIdx.y * 128, col0 = blockIdx.x * 128;
    const int lane = tid & 63, wave = tid >> 6;
    const int wr = (wave >> 1) * 64, wc = (wave & 1) * 64;

    if (EPI >= 2) {
        for (int e = tid; e < 128 * 12; e += 256)
            bns[(e / 12) * 13 + (e % 12)] = extA[(long)(row0 + e / 12) * 12 + e % 12];
        for (int e = tid; e < 12 * 128; e += 256)
            exb[e] = extB[(long)(e >> 7) * N + col0 + (e & 127)];
    }

    f32x4 acc[4][4];
    #pragma unroll
    for (int m = 0; m < 4; ++m)
        #pragma unroll
        for (int n = 0; n < 4; ++n) {
            acc[m][n][0] = 0.f; acc[m][n][1] = 0.f;
            acc[m][n][2] = 0.f; acc[m][n][3] = 0.f;
        }

    const int rA = lane & 15;
    const int ko = (lane >> 4) * 8;
    const int srow = tid >> 2;
    const int skk = (tid & 3) * 8;

    for (int k0 = 0; k0 < K; k0 += 64) {
        #pragma unroll
        for (int hf = 0; hf < 2; ++hf) {
            #pragma unroll
            for (int i = 0; i < 2; ++i) {
                const long ga = (long)(row0 + i * 64 + srow) * K + k0 + hf * 32 + skk;
                __builtin_amdgcn_global_load_lds(
                    (const __attribute__((address_space(1))) void*)(A + ga),
                    (__attribute__((address_space(3))) void*)(&As[hf][0] + i * 2048 + wave * 512),
                    16, 0, 0);
                const long gb = (long)(col0 + i * 64 + srow) * K + k0 + hf * 32 + skk;
                __builtin_amdgcn_global_load_lds(
                    (const __attribute__((address_space(1))) void*)(BT + gb),
                    (__attribute__((address_space(3))) void*)(&Bs[hf][0] + i * 2048 + wave * 512),
                    16, 0, 0);
            }
        }
        __syncthreads();
        #pragma unroll
        for (int hf = 0; hf < 2; ++hf) {
            bf16x8 af[4], bfr[4];
            #pragma unroll
            for (int m = 0; m < 4; ++m)
                af[m] = *(const bf16x8*)(&As[hf][0] + (wr + m * 16 + rA) * 32 + ko);
            #pragma unroll
            for (int n = 0; n < 4; ++n)
                bfr[n] = *(const bf16x8*)(&Bs[hf][0] + (wc + n * 16 + rA) * 32 + ko);
            #pragma unroll
            for (int m = 0; m < 4; ++m)
                #pragma unroll
                for (int n = 0; n < 4; ++n)
                    acc[m][n] = __builtin_amdgcn_mfma_f32_16x16x32_bf16(af[m], bfr[n], acc[m][n], 0, 0, 0);
        }
        __syncthreads();
    }

    const int crow = (lane >> 4) * 4;
    const int ccol = lane & 15;
    #pragma unroll
    for (int m = 0; m < 4; ++m) {
        #pragma unroll
        for (int n = 0; n < 4; ++n) {
            #pragma unroll
            for (int r = 0; r < 4; ++r) {
                const int rl = wr + m * 16 + crow + r;
                const int cl = wc + n * 16 + ccol;
                float vv = acc[m][n][r];
                if (EPI >= 2) {
                    vv += bias[col0 + cl];
                    #pragma unroll
                    for (int j = 0; j < 12; ++j) vv += bns[rl * 13 + j] * exb[j * 128 + cl];
                    vv = 0.5f * vv * (1.f + erff(vv * 0.70710678118654752f));
                }
                const long off = (long)(row0 + rl) * N + col0 + cl;
                if (EPI == 0) ((float*)Cout)[off] = vv;
                else ((ushort*)Cout)[off] = f2bf(vv);
            }
        }
    }
}

// ---------------------------------------------------------------------------
// Transpose + cast to bf16: W[K][N] f32 -> WT[N][K] bf16.
// ---------------------------------------------------------------------------
__global__ __launch_bounds__(256) void transpose_cast(const float* __restrict__ W,
    ushort* __restrict__ WT, int K, int N)
{
    __shared__ float t[32][33];
    const int k0 = blockIdx.y * 32, n0 = blockIdx.x * 32;
    const int c = threadIdx.x & 31, r8 = threadIdx.x >> 5;
    #pragma unroll
    for (int rr = 0; rr < 4; ++rr) {
        const int r = r8 + rr * 8;
        t[r][c] = W[(long)(k0 + r) * N + n0 + c];
    }
    __syncthreads();
    #pragma unroll
    for (int rr = 0; rr < 4; ++rr) {
        const int r = r8 + rr * 8;
        WT[(long)(n0 + r) * K + k0 + c] = f2bf(t[c][r]);
    }
}

__global__ __launch_bounds__(256) void cast_bf16(const float* __restrict__ x,
    ushort* __restrict__ y)
{
    const long i = ((long)blockIdx.x * 256 + threadIdx.x) * 4;
    const float4 v = *(const float4*)(x + i);
    ushort4 o;
    o.x = f2bf(v.x); o.y = f2bf(v.y); o.z = f2bf(v.z); o.w = f2bf(v.w);
    *(ushort4*)(y + i) = o;
}

// ---------------------------------------------------------------------------
// Small-N GEMM. MODE 0: sigmoid. MODE 1: +bias, per-head softmax over triples.
// ---------------------------------------------------------------------------
template<int NOUT, int MODE, typename TA>
__global__ __launch_bounds__(256) void gemm_smallN(const TA* __restrict__ A,
    const float* __restrict__ Bm, const float* __restrict__ bias,
    float* __restrict__ Cm, int K)
{
    __shared__ float part[4][NOUT];
    __shared__ float sm[NOUT];
    const int m = blockIdx.x, tid = threadIdx.x;
    const TA* ar = A + (long)m * K;
    float acc[NOUT];
    #pragma unroll
    for (int j = 0; j < NOUT; ++j) acc[j] = 0.f;
    for (int k = tid; k < K; k += 256) {
        const float a = ldf(ar[k]);
        #pragma unroll
        for (int j = 0; j < NOUT; ++j) acc[j] += a * Bm[(long)k * NOUT + j];
    }
    #pragma unroll
    for (int j = 0; j < NOUT; ++j)
        for (int off = 32; off > 0; off >>= 1) acc[j] += __shfl_down(acc[j], off);
    const int wid = tid >> 6, lane = tid & 63;
    if (lane == 0) {
        #pragma unroll
        for (int j = 0; j < NOUT; ++j) part[wid][j] = acc[j];
    }
    __syncthreads();
    if (tid < NOUT) {
        float s = part[0][tid] + part[1][tid] + part[2][tid] + part[3][tid];
        if (MODE == 0) {
            Cm[(long)m * NOUT + tid] = 1.f / (1.f + expf(-s));
        } else {
            sm[tid] = s + bias[tid];
        }
    }
    if (MODE == 1) {
        __syncthreads();
        if (tid < NOUT) {
            const int hh = tid / 3, r = tid - hh * 3;
            const float a0 = sm[hh * 3], a1 = sm[hh * 3 + 1], a2 = sm[hh * 3 + 2];
            const float mx = fmaxf(a0, fmaxf(a1, a2));
            const float e0 = expf(a0 - mx), e1 = expf(a1 - mx), e2 = expf(a2 - mx);
            const float mine = (r == 0) ? e0 : ((r == 1) ? e1 : e2);
            Cm[(long)m * NOUT + tid] = mine / (e0 + e1 + e2);
        }
    }
}

// ---------------------------------------------------------------------------
// Depthwise causal conv (k=4) + SiLU, fp32 -> fp32.
// ---------------------------------------------------------------------------
__global__ __launch_bounds__(256) void conv4_silu(const float* __restrict__ x,
    const float* __restrict__ wc, float* __restrict__ y)
{
    const long idx = (long)blockIdx.x * 256 + threadIdx.x;
    const int c = (int)(idx & 1023);
    const long bl = idx >> 10;
    const int l = (int)(bl & 2047);
    const long b = bl >> 11;
    const float* xp = x + b * 2048 * 1024 + c;
    const float* wp = wc + c * 4;
    float s = 0.f;
    #pragma unroll
    for (int t = 0; t < 4; ++t) {
        const int ll = l - 3 + t;
        if (ll >= 0) s += xp[(long)ll * 1024] * wp[t];
    }
    y[idx] = s / (1.f + expf(-s));
}

// ---------------------------------------------------------------------------
// l2 normalize rows of 256 (fp32 in), write bf16.
// ---------------------------------------------------------------------------
__global__ __launch_bounds__(256) void l2norm_bf16(const float* __restrict__ x,
    ushort* __restrict__ y)
{
    const long wid = ((long)blockIdx.x * 256 + threadIdx.x) >> 6;
    const int lane = threadIdx.x & 63;
    const float4 xv = *(const float4*)(x + wid * 256 + lane * 4);
    float ss = xv.x * xv.x + xv.y * xv.y + xv.z * xv.z + xv.w * xv.w;
    for (int off = 32; off > 0; off >>= 1) ss += __shfl_down(ss, off);
    ss = __shfl(ss, 0);
    const float inv = rsqrtf(ss + 1e-6f);
    ushort4 o;
    o.x = f2bf(xv.x * inv); o.y = f2bf(xv.y * inv);
    o.z = f2bf(xv.z * inv); o.w = f2bf(xv.w * inv);
    *(ushort4*)(y + wid * 256 + lane * 4) = o;
}

// ---------------------------------------------------------------------------
// Chunk prep (MFMA M/aloc). Outputs: u (f32), w16 [blk][32][256] bf16,
// kT16 [blk][256][32] bf16, al16 [blk][32][32] bf16.
// Staging: kn16/kb16 [32][264] bf16 (uint4 vectorized), vb [32][260] f32
// (float4). M = kb@kn^T and aloc = q@kn^T via mfma_16x16x32 (4 waves, 2x2
// tiles, K=256); aloc A-frags read direct from global q16 (scan-verified
// pattern). Doubling + u/w stay fp32 VALU (inversion numerics preserved).
// LDS ~75.6 KB -> 2 blocks/CU.
// ---------------------------------------------------------------------------
__global__ __launch_bounds__(256) void chunk_prep(
    const ushort* __restrict__ qn, const ushort* __restrict__ kn,
    const float* __restrict__ v, const float* __restrict__ beta,
    float* __restrict__ u, ushort* __restrict__ w16,
    ushort* __restrict__ kT16, ushort* __restrict__ al16)
{
    __shared__ __align__(16) ushort kn16[32 * 264];
    __shared__ __align__(16) ushort kb16[32 * 264];
    __shared__ __align__(16) float  vb[32 * 260];
    __shared__ float Ms[32 * 33];
    __shared__ float Rs[32 * 33];
    __shared__ float bet[32];
    const int blk = blockIdx.x;
    const int n = blk & 63;
    const int bh = blk >> 6;
    const int h = bh & 3;
    const int b = bh >> 2;
    const int tid = threadIdx.x;
    const long lbase = (long)b * 2048 + n * 32;

    if (tid < 32) bet[tid] = beta[(lbase + tid) * 4 + h];
    __syncthreads();

    // ---- vectorized staging: kn16 + kb16 (bf16), vb (f32)
    #pragma unroll
    for (int it = 0; it < 4; ++it) {
        const int e2 = tid + it * 256;
        const int c = e2 >> 5, d8 = (e2 & 31) * 8;
        const uint4 kv = *(const uint4*)(kn + (lbase + c) * 1024 + h * 256 + d8);
        *(uint4*)&kn16[c * 264 + d8] = kv;
        const float bc = bet[c];
        uint4 kb;
        kb.x = (uint)f2bf(bf2f((ushort)(kv.x & 0xffffu)) * bc) |
               ((uint)f2bf(bf2f((ushort)(kv.x >> 16)) * bc) << 16);
        kb.y = (uint)f2bf(bf2f((ushort)(kv.y & 0xffffu)) * bc) |
               ((uint)f2bf(bf2f((ushort)(kv.y >> 16)) * bc) << 16);
        kb.z = (uint)f2bf(bf2f((ushort)(kv.z & 0xffffu)) * bc) |
               ((uint)f2bf(bf2f((ushort)(kv.z >> 16)) * bc) << 16);
        kb.w = (uint)f2bf(bf2f((ushort)(kv.w & 0xffffu)) * bc) |
               ((uint)f2bf(bf2f((ushort)(kv.w >> 16)) * bc) << 16);
        *(uint4*)&kb16[c * 264 + d8] = kb;
    }
    #pragma unroll
    for (int it = 0; it < 8; ++it) {
        const int e2 = tid + it * 256;
        const int c = e2 >> 6, d4 = (e2 & 63) * 4;
        float4 vv = *(const float4*)(v + (lbase + c) * 1024 + h * 256 + d4);
        const float bc = bet[c];
        vv.x *= bc; vv.y *= bc; vv.z *= bc; vv.w *= bc;
        *(float4*)&vb[c * 260 + d4] = vv;
    }
    __syncthreads();

    // ---- kT16 out (from kn16; value already bf16)
    for (int e = tid; e < 8192; e += 256)
        kT16[(long)blk * 8192 + e] = kn16[(e & 31) * 264 + (e >> 5)];

    // ---- M = kb@kn^T (strict lower, negated) and aloc = q@kn^T (incl lower)
    // via MFMA: 4 waves, wave w -> 16x16 tile (w>>1, w&1), K=256.
    const int lane = tid & 63, wave = tid >> 6;
    const int wr2 = (wave >> 1) * 16, wc2 = (wave & 1) * 16;
    const int rA = lane & 15, ko = (lane >> 4) * 8;
    {
        f32x4 accM, accA;
        accM[0] = 0.f; accM[1] = 0.f; accM[2] = 0.f; accM[3] = 0.f;
        accA[0] = 0.f; accA[1] = 0.f; accA[2] = 0.f; accA[3] = 0.f;
        const ushort* qrow = qn + (lbase + wr2 + rA) * 1024 + h * 256 + ko;
        #pragma unroll
        for (int ks = 0; ks < 8; ++ks) {
            const bf16x8 bfK = *(const bf16x8*)&kn16[(wc2 + rA) * 264 + ks * 32 + ko];
            const bf16x8 afM = *(const bf16x8*)&kb16[(wr2 + rA) * 264 + ks * 32 + ko];
            accM = __builtin_amdgcn_mfma_f32_16x16x32_bf16(afM, bfK, accM, 0, 0, 0);
            const bf16x8 afQ = *(const bf16x8*)(qrow + ks * 32);
            accA = __builtin_amdgcn_mfma_f32_16x16x32_bf16(afQ, bfK, accA, 0, 0, 0);
        }
        const int ccol = lane & 15, crow = (lane >> 4) * 4;
        #pragma unroll
        for (int r = 0; r < 4; ++r) {
            const int i = wr2 + crow + r, j = wc2 + ccol;
            const float mv = (i > j) ? -accM[r] : 0.f;
            Ms[i * 33 + j] = mv;
            Rs[i * 33 + j] = mv + ((i == j) ? 1.f : 0.f);
            al16[(long)blk * 1024 + i * 32 + j] = f2bf((i >= j) ? accA[r] : 0.f);
        }
    }
    __syncthreads();

    // ---- R = (I+M)(I+M^2)(I+M^4)(I+M^8)(I+M^16)  (fp32 VALU, unchanged)
    const int j = tid & 31, i0 = tid >> 5;
    for (int it = 0; it < 4; ++it) {
        float p4[4] = {0.f, 0.f, 0.f, 0.f};
        for (int kk = 0; kk < 32; ++kk) {
            const float pb = Ms[kk * 33 + j];
            #pragma unroll
            for (int ii = 0; ii < 4; ++ii) p4[ii] += Ms[(i0 + 8 * ii) * 33 + kk] * pb;
        }
        __syncthreads();
        #pragma unroll
        for (int ii = 0; ii < 4; ++ii) Ms[(i0 + 8 * ii) * 33 + j] = p4[ii];
        __syncthreads();
        float r4[4] = {0.f, 0.f, 0.f, 0.f};
        for (int kk = 0; kk < 32; ++kk) {
            const float pb = Ms[kk * 33 + j];
            #pragma unroll
            for (int ii = 0; ii < 4; ++ii) r4[ii] += Rs[(i0 + 8 * ii) * 33 + kk] * pb;
        }
        __syncthreads();
        #pragma unroll
        for (int ii = 0; ii < 4; ++ii) Rs[(i0 + 8 * ii) * 33 + j] += r4[ii];
        __syncthreads();
    }

    // ---- u = R @ vb, w = R @ kb  (fp32 VALU; thread = dd column)
    {
        const int dd = tid;
        float accU[32], accW[32];
        #pragma unroll
        for (int r = 0; r < 32; ++r) { accU[r] = 0.f; accW[r] = 0.f; }
        for (int kk = 0; kk < 32; ++kk) {
            const float vv = vb[kk * 260 + dd];
            const float bb = bf2f(kb16[kk * 264 + dd]);
            #pragma unroll
            for (int r = 0; r < 32; ++r) {
                const float rr = Rs[r * 33 + kk];
                accU[r] += rr * vv;
                accW[r] += rr * bb;
            }
        }
        const long base = (long)blk * 32;
        #pragma unroll
        for (int r = 0; r < 32; ++r) {
            u  [(base + r) * 256 + dd] = accU[r];
            w16[(base + r) * 256 + dd] = f2bf(accW[r]);
        }
    }
}

// ---------------------------------------------------------------------------
// MFMA delta scan, 256 x 1-wave blocks, ALL-REGISTER operand staging.
// __launch_bounds__(64,1) unlocks 512 VGPR/wave. All operand frags prefetched
// one phase ahead via plain global loads (per-register dep tracking). Sb/Ub
// LDS roundtrips (C-layout -> B-frag swap) on distinct static arrays.
// Per chunk: u' = u - w@S ; o = q@S + aloc@u' ; S += kT@u'
// ---------------------------------------------------------------------------
__global__ __launch_bounds__(64, 1) void delta_scan_mfma(
    const ushort* __restrict__ q16, const ushort* __restrict__ kT16,
    const ushort* __restrict__ w16, const float* __restrict__ u,
    const ushort* __restrict__ al16, float* __restrict__ dt)
{
    __shared__ __align__(16) ushort Sb[16 * 264];
    __shared__ __align__(16) ushort Ub[16 * 40];
    const int blk = blockIdx.x;
    const int bh = blk & 15;
    const int sl = blk >> 4;
    const int h = bh & 3;
    const int b = bh >> 2;
    const int v0 = sl * 16;
    const int lane = threadIdx.x;
    const int col = lane & 15;
    const int grp = lane >> 4;

    const ushort* wp  = w16  + ((long)bh * 64 * 32 + col) * 256 + grp * 8;
    const ushort* qp  = q16  + ((long)b * 2048 + col) * 1024 + h * 256 + grp * 8;
    const ushort* kp  = kT16 + ((long)bh * 64 * 256 + col) * 32 + grp * 8;
    const ushort* ap  = al16 + ((long)bh * 64 * 32 + col) * 32 + grp * 8;
    const float*  Ug  = u    + ((long)bh * 64 * 32 + grp * 4) * 256 + v0 + col;
    float*        dp  = dt   + ((long)b * 2048 + grp * 4) * 1024 + h * 256 + v0 + col;

    f32x4 S[16];
    #pragma unroll
    for (int t = 0; t < 16; ++t) { S[t][0] = 0.f; S[t][1] = 0.f; S[t][2] = 0.f; S[t][3] = 0.f; }

    bf16x8 wf[2][8], qf[2][8], kf[16], alf[2], sf[8];
    float upre[8];

    #pragma unroll
    for (int kb = 0; kb < 8; ++kb)
        #pragma unroll
        for (int e = 0; e < 8; ++e) sf[kb][e] = (__bf16)0.f;

    #pragma unroll
    for (int rt = 0; rt < 2; ++rt)
        #pragma unroll
        for (int kb = 0; kb < 8; ++kb) {
            wf[rt][kb] = *(const bf16x8*)(wp + rt * 4096 + kb * 32);
            qf[rt][kb] = *(const bf16x8*)(qp + (long)rt * 16384 + kb * 32);
        }
    #pragma unroll
    for (int t = 0; t < 16; ++t) kf[t] = *(const bf16x8*)(kp + t * 512);
    alf[0] = *(const bf16x8*)(ap);
    alf[1] = *(const bf16x8*)(ap + 512);
    #pragma unroll
    for (int rt = 0; rt < 2; ++rt)
        #pragma unroll
        for (int r = 0; r < 4; ++r)
            upre[rt * 4 + r] = Ug[rt * 4096 + r * 256];

    for (int n = 0; n < 64; ++n) {
        // --- u' = u - w@S
        f32x4 up[2];
        #pragma unroll
        for (int rt = 0; rt < 2; ++rt) {
            f32x4 a; a[0] = 0.f; a[1] = 0.f; a[2] = 0.f; a[3] = 0.f;
            #pragma unroll
            for (int kb = 0; kb < 8; ++kb)
                a = __builtin_amdgcn_mfma_f32_16x16x32_bf16(wf[rt][kb], sf[kb], a, 0, 0, 0);
            #pragma unroll
            for (int r = 0; r < 4; ++r)
                up[rt][r] = upre[rt * 4 + r] - a[r];
        }
        if (n < 63) {
            #pragma unroll
            for (int rt = 0; rt < 2; ++rt)
                #pragma unroll
                for (int kb = 0; kb < 8; ++kb)
                    wf[rt][kb] = *(const bf16x8*)(wp + (long)(n + 1) * 8192 + rt * 4096 + kb * 32);
        }

        // --- u' C-layout -> B-frag via Ub
        #pragma unroll
        for (int rt = 0; rt < 2; ++rt) {
            ushort4 p;
            p.x = f2bf(up[rt][0]); p.y = f2bf(up[rt][1]);
            p.z = f2bf(up[rt][2]); p.w = f2bf(up[rt][3]);
            *(ushort4*)&Ub[col * 40 + rt * 16 + grp * 4] = p;
        }
        const bf16x8 uf = *(const bf16x8*)&Ub[col * 40 + grp * 8];

        // --- o = q@S + aloc@u' ; store to dt
        #pragma unroll
        for (int rt = 0; rt < 2; ++rt) {
            f32x4 a; a[0] = 0.f; a[1] = 0.f; a[2] = 0.f; a[3] = 0.f;
            #pragma unroll
            for (int kb = 0; kb < 8; ++kb)
                a = __builtin_amdgcn_mfma_f32_16x16x32_bf16(qf[rt][kb], sf[kb], a, 0, 0, 0);
            a = __builtin_amdgcn_mfma_f32_16x16x32_bf16(alf[rt], uf, a, 0, 0, 0);
            #pragma unroll
            for (int r = 0; r < 4; ++r)
                dp[(long)n * 32768 + rt * 16384 + r * 1024] = a[r];
        }
        if (n < 63) {
            #pragma unroll
            for (int rt = 0; rt < 2; ++rt)
                #pragma unroll
                for (int kb = 0; kb < 8; ++kb)
                    qf[rt][kb] = *(const bf16x8*)(qp + (long)(n + 1) * 32768 + (long)rt * 16384 + kb * 32);
            alf[0] = *(const bf16x8*)(ap + (long)(n + 1) * 1024);
            alf[1] = *(const bf16x8*)(ap + (long)(n + 1) * 1024 + 512);
        }

        // --- S += kT @ u'
        #pragma unroll
        for (int t = 0; t < 16; ++t)
            S[t] = __builtin_amdgcn_mfma_f32_16x16x32_bf16(kf[t], uf, S[t], 0, 0, 0);
        if (n < 63) {
            #pragma unroll
            for (int t = 0; t < 16; ++t)
                kf[t] = *(const bf16x8*)(kp + (long)(n + 1) * 8192 + t * 512);
            #pragma unroll
            for (int rt = 0; rt < 2; ++rt)
                #pragma unroll
                for (int r = 0; r < 4; ++r)
                    upre[rt * 4 + r] = Ug[(long)(n + 1) * 8192 + rt * 4096 + r * 256];
        }

        // --- S C-layout -> B-frag via Sb (sf for next chunk)
        #pragma unroll
        for (int t = 0; t < 16; ++t) {
            ushort4 p;
            p.x = f2bf(S[t][0]); p.y = f2bf(S[t][1]);
            p.z = f2bf(S[t][2]); p.w = f2bf(S[t][3]);
            *(ushort4*)&Sb[col * 264 + t * 16 + grp * 4] = p;
        }
        #pragma unroll
        for (int kb = 0; kb < 8; ++kb)
            sf[kb] = *(const bf16x8*)&Sb[col * 264 + kb * 32 + grp * 8];
    }
}

// ---------------------------------------------------------------------------
// Multiscale causal depthwise conv -> bf16 out. Flat-index identity:
// y[(b*2048+l)*3072 + sc*1024 + c]. Thread = (b, c, 8-l window).
// ---------------------------------------------------------------------------
__global__ __launch_bounds__(256) void ms_conv(const float* __restrict__ v,
    const float* __restrict__ w3, const float* __restrict__ w15,
    const float* __restrict__ w31, ushort* __restrict__ y)
{
    const int bid = blockIdx.x;
    const int b = bid >> 10;
    const int oct = (bid >> 2) & 255;
    const int c = ((bid & 3) << 8) + threadIdx.x;
    const int l0 = oct << 3;
    const float* vb = v + ((long)b * 2048) * 1024 + c;
    ushort* yb = y + ((long)b * 2048) * 3072 + c;

    float win[38];
    #pragma unroll
    for (int t = 0; t < 38; ++t) {
        const int ll = l0 - 30 + t;
        win[t] = (ll >= 0) ? vb[(long)ll * 1024] : 0.f;
    }
    {
        float W[31];
        #pragma unroll
        for (int t = 0; t < 31; ++t) W[t] = w31[c * 31 + t];
        #pragma unroll
        for (int j = 0; j < 8; ++j) {
            float s = 0.f;
            #pragma unroll
            for (int t = 0; t < 31; ++t) s += win[j + t] * W[t];
            yb[(long)(l0 + j) * 3072 + 2048] = f2bf(s);
        }
    }
    {
        float W[15];
        #pragma unroll
        for (int t = 0; t < 15; ++t) W[t] = w15[c * 15 + t];
        #pragma unroll
        for (int j = 0; j < 8; ++j) {
            float s = 0.f;
            #pragma unroll
            for (int t = 0; t < 15; ++t) s += win[j + 16 + t] * W[t];
            yb[(long)(l0 + j) * 3072 + 1024] = f2bf(s);
        }
    }
    {
        float W[3];
        #pragma unroll
        for (int t = 0; t < 3; ++t) W[t] = w3[c * 3 + t];
        #pragma unroll
        for (int j = 0; j < 8; ++j) {
            float s = 0.f;
            #pragma unroll
            for (int t = 0; t < 3; ++t) s += win[j + 28 + t] * W[t];
            yb[(long)(l0 + j) * 3072] = f2bf(s);
        }
    }
}

// ---------------------------------------------------------------------------
// bn features: bn[bl,12] = [mean|ms| | mean|dt| | mean|v|] per head.
// ---------------------------------------------------------------------------
__global__ __launch_bounds__(256) void build_bn(const float* __restrict__ ms,
    const float* __restrict__ dt, const float* __restrict__ v,
    float* __restrict__ bn)
{
    const int bl = blockIdx.x, tid = threadIdx.x;
    const long rb = (long)bl * 1024;
    const int wid = tid >> 6, lane = tid & 63;
    const long base = rb + wid * 256 + lane * 4;
    float* g = bn + (long)bl * 12;
    float4 a;
    float s;
    a = *(const float4*)(ms + base);
    s = fabsf(a.x) + fabsf(a.y) + fabsf(a.z) + fabsf(a.w);
    for (int off = 32; off > 0; off >>= 1) s += __shfl_down(s, off);
    if (lane == 0) g[wid] = s * (1.f / 256.f);
    a = *(const float4*)(dt + base);
    s = fabsf(a.x) + fabsf(a.y) + fabsf(a.z) + fabsf(a.w);
    for (int off = 32; off > 0; off >>= 1) s += __shfl_down(s, off);
    if (lane == 0) g[4 + wid] = s * (1.f / 256.f);
    a = *(const float4*)(v + base);
    s = fabsf(a.x) + fabsf(a.y) + fabsf(a.z) + fabsf(a.w);
    for (int off = 32; off > 0; off >>= 1) s += __shfl_down(s, off);
    if (lane == 0) g[8 + wid] = s * (1.f / 256.f);
}

// ---------------------------------------------------------------------------
// Blend + per-head RMSNorm * o_norm_w -> bf16 out.
// ---------------------------------------------------------------------------
__global__ __launch_bounds__(256) void blend_rms(const float* __restrict__ ms,
    const float* __restrict__ dt, const float* __restrict__ v,
    const float* __restrict__ wts, const float* __restrict__ onw,
    ushort* __restrict__ o)
{
    const int bl = blockIdx.x, tid = threadIdx.x;
    const int wid = tid >> 6, lane = tid & 63;
    const long base = (long)bl * 1024 + wid * 256 + lane * 4;
    const float* wr = wts + (long)bl * 12 + wid * 3;
    const float w0 = wr[0], w1 = wr[1], w2 = wr[2];
    const float4 m = *(const float4*)(ms + base);
    const float4 d = *(const float4*)(dt + base);
    const float4 x = *(const float4*)(v + base);
    float4 ov;
    ov.x = w0 * m.x + w1 * d.x + w2 * x.x;
    ov.y = w0 * m.y + w1 * d.y + w2 * x.y;
    ov.z = w0 * m.z + w1 * d.z + w2 * x.z;
    ov.w = w0 * m.w + w1 * d.w + w2 * x.w;
    float ss = ov.x * ov.x + ov.y * ov.y + ov.z * ov.z + ov.w * ov.w;
    for (int off = 32; off > 0; off >>= 1) ss += __shfl_down(ss, off);
    ss = __shfl(ss, 0);
    const float inv = rsqrtf(ss * (1.f / 256.f) + 1e-5f);
    const float4 nw = *(const float4*)(onw + lane * 4);
    ushort4 ob;
    ob.x = f2bf(ov.x * inv * nw.x); ob.y = f2bf(ov.y * inv * nw.y);
    ob.z = f2bf(ov.z * inv * nw.z); ob.w = f2bf(ov.w * inv * nw.w);
    *(ushort4*)(o + base) = ob;
}

// ---------------------------------------------------------------------------
extern "C" void kernel_launch(void* const* d_in, const int* in_sizes, int n_in,
                              void* d_out, int out_size, void* d_ws, size_t ws_size,
                              hipStream_t stream)
{
    (void)in_sizes; (void)n_in; (void)out_size; (void)ws_size;
    const float* hid   = (const float*)d_in[0];
    const float* Wq    = (const float*)d_in[1];
    const float* Wk    = (const float*)d_in[2];
    const float* Wv    = (const float*)d_in[3];
    const float* Wb    = (const float*)d_in[4];
    const float* cq    = (const float*)d_in[5];
    const float* ck    = (const float*)d_in[6];
    const float* cv    = (const float*)d_in[7];
    const float* w3    = (const float*)d_in[8];
    const float* w15   = (const float*)d_in[9];
    const float* w31   = (const float*)d_in[10];
    const float* kmix  = (const float*)d_in[11];
    const float* cmix  = (const float*)d_in[12];
    const float* fw1   = (const float*)d_in[13];
    const float* fb1   = (const float*)d_in[14];
    const float* fw2   = (const float*)d_in[15];
    const float* fb2   = (const float*)d_in[16];
    const float* onw   = (const float*)d_in[17];
    const float* Wo    = (const float*)d_in[18];
    float* out = (float*)d_out;

    // ---- workspace carve (peak ~195 MiB) ----
    const size_t MiB = 1024 * 1024;
    char* W = (char*)d_ws;
    float*  s0    = (float*)(W);              // qlin -> u(f32) -> yms[lo] -> hdn16
    char*   s1c   = W + 32 * MiB;             // qtmp -> w16|kT16 -> yms[hi] -> msout
    float*  s1    = (float*)s1c;
    float*  s2    = (float*)(W + 64 * MiB);   // vlin -> dt
    char*   s3    = W + 96 * MiB;             // q16|k16 -> mix16|ofin16
    float*  s4    = (float*)(W + 128 * MiB);  // v (long-lived)
    ushort* hid16 = (ushort*)(W + 160 * MiB);
    ushort* WqT   = (ushort*)(W + 176 * MiB);
    ushort* WkT   = WqT   + 1024 * 1024;
    ushort* WvT   = WkT   + 1024 * 1024;
    ushort* cmixT = WvT   + 1024 * 1024;
    ushort* WoT   = cmixT + 1024 * 1024;
    ushort* fw1T  = WoT   + 1024 * 1024;      // [2048][1024]
    ushort* kmixT = fw1T  + 2048 * 1024;      // [256][768]
    float*  beta  = (float*)(W + 191 * MiB);  // 128 KB
    ushort* al16  = (ushort*)(W + 191 * MiB + 128 * 1024);  // 2 MiB
    float*  bnf   = (float*)(W + 193 * MiB + 128 * 1024);   // 384 KB
    float*  wts   = bnf + 98304;                            // 384 KB

    ushort* q16    = (ushort*)s3;
    ushort* k16    = (ushort*)(s3 + 16 * MiB);
    ushort* mix16  = q16;
    ushort* ofin16 = k16;
    ushort* yms16  = (ushort*)s0;             // 48 MiB spans s0+s1
    ushort* hdn16  = (ushort*)s0;
    float*  qlin = s0; float* qtmp = s1;
    float*  u = s0;
    ushort* w16  = (ushort*)s1c;              // 16 MiB
    ushort* kT16 = (ushort*)(s1c + 16 * MiB); // 16 MiB
    float*  dt = s2; float* v = s4; float* msout = s1;

    const dim3 T256(256);
    // 0. casts / weight transposes
    cast_bf16<<<8192, T256, 0, stream>>>(hid, hid16);
    transpose_cast<<<dim3(32, 32), T256, 0, stream>>>(Wq, WqT, 1024, 1024);
    transpose_cast<<<dim3(32, 32), T256, 0, stream>>>(Wk, WkT, 1024, 1024);
    transpose_cast<<<dim3(32, 32), T256, 0, stream>>>(Wv, WvT, 1024, 1024);
    transpose_cast<<<dim3(32, 32), T256, 0, stream>>>(cmix, cmixT, 1024, 1024);
    transpose_cast<<<dim3(32, 32), T256, 0, stream>>>(Wo, WoT, 1024, 1024);
    transpose_cast<<<dim3(64, 32), T256, 0, stream>>>(fw1, fw1T, 1024, 2048);
    transpose_cast<<<dim3(8, 24), T256, 0, stream>>>(kmix, kmixT, 768, 256);
    // 1. q pipeline
    gemm_mfma<0><<<dim3(8, 64), T256, 0, stream>>>(hid16, WqT, nullptr, nullptr, nullptr, qlin, 8192, 1024, 1024);
    conv4_silu<<<32768, T256, 0, stream>>>(qlin, cq, qtmp);
    l2norm_bf16<<<8192, T256, 0, stream>>>(qtmp, q16);
    // 2. k pipeline
    gemm_mfma<0><<<dim3(8, 64), T256, 0, stream>>>(hid16, WkT, nullptr, nullptr, nullptr, qlin, 8192, 1024, 1024);
    conv4_silu<<<32768, T256, 0, stream>>>(qlin, ck, qtmp);
    l2norm_bf16<<<8192, T256, 0, stream>>>(qtmp, k16);
    // 3. v pipeline
    gemm_mfma<0><<<dim3(8, 64), T256, 0, stream>>>(hid16, WvT, nullptr, nullptr, nullptr, qlin, 8192, 1024, 1024);
    conv4_silu<<<32768, T256, 0, stream>>>(qlin, cv, v);
    // 4. beta
    gemm_smallN<4, 0><<<8192, T256, 0, stream>>>(hid, Wb, nullptr, beta, 1024);
    // 5. delta rule: prep (MFMA M/aloc) + scan (all-register staging)
    chunk_prep<<<1024, T256, 0, stream>>>(q16, k16, v, beta, u, w16, kT16, al16);
    delta_scan_mfma<<<256, dim3(64), 0, stream>>>(q16, kT16, w16, u, al16, dt);
    // 6. multiscale conv branch
    ms_conv<<<4096, T256, 0, stream>>>(v, w3, w15, w31, yms16);
    gemm_mfma<1><<<dim3(2, 256), T256, 0, stream>>>(yms16, kmixT, nullptr, nullptr, nullptr, mix16, 32768, 256, 768);
    gemm_mfma<0><<<dim3(8, 64), T256, 0, stream>>>(mix16, cmixT, nullptr, nullptr, nullptr, msout, 8192, 1024, 1024);
    // 7. fusion gate
    build_bn<<<8192, T256, 0, stream>>>(msout, dt, v, bnf);
    gemm_mfma<3><<<dim3(16, 64), T256, 0, stream>>>(hid16, fw1T, fb1, bnf, fw1 + 1024L * 2048, hdn16, 8192, 2048, 1024);
    gemm_smallN<12, 1><<<8192, T256, 0, stream>>>(hdn16, fw2, fb2, wts, 2048);
    // 8. blend + output projection
    blend_rms<<<8192, T256, 0, stream>>>(msout, dt, v, wts, onw, ofin16);
    gemm_mfma<0><<<dim3(8, 64), T256, 0, stream>>>(ofin16, WoT, nullptr, nullptr, nullptr, out, 8192, 1024, 1024);
}